// Round 4
// baseline (298.785 us; speedup 1.0000x reference)
//
#include <hip/hip_runtime.h>

// B=8, S=2048, D=1024 banded attention, window +-20.
// out[b,q,:] = softmax_k( q^T W key_k , |q-k|<=20 ) @ keys
// b_reduce: per-q constant on every logit -> cancels in softmax -> unused.
//
// R7 == R5/R6 resubmitted (both prior benches were container/infra failures;
// full OOB/hang audit found no device-side fault path — see session journal).
//  - attn_v3: QK^T fragments streamed DIRECTLY from global (f16 QT / fp32 keys
//    cvt in-reg) -> zero LDS staging, zero barriers before softmax. PV with
//    explicit 8-query register blocking + float4 key loads/out stores.
//  - gemm_f16t: grid n-fastest (8,128) so the 8 n-tile blocks of an m-panel
//    are concurrent -> A fetched once through L3 instead of 8x from HBM.
//  - cvt_q_f16 / cvt_w_t unchanged. Fallback R3 path kept (ws too small).

#define BATCH 8
#define SEQ   2048
#define DIM   1024
#define WIN   20

typedef _Float16 half8  __attribute__((ext_vector_type(8)));
typedef _Float16 half4v __attribute__((ext_vector_type(4)));
typedef float    f32x4  __attribute__((ext_vector_type(4)));

#define GLOAD_LDS16(gsrc, ldst)                                                        \
    __builtin_amdgcn_global_load_lds(                                                  \
        (const __attribute__((address_space(1))) void*)(gsrc),                         \
        (__attribute__((address_space(3))) void*)(ldst), 16, 0, 0)

// ---------------------------------------------------------------------------
// Prep 1: Q fp32 -> f16, vectorized 8/thread, grid-stride.
// ---------------------------------------------------------------------------
__global__ __launch_bounds__(256) void cvt_q_f16(const float* __restrict__ in,
                                                 _Float16* __restrict__ out) {
    const int n8 = (BATCH * SEQ * DIM) / 8;
    for (int i = blockIdx.x * 256 + threadIdx.x; i < n8; i += gridDim.x * 256) {
        const float4 a = ((const float4*)in)[2 * i];
        const float4 b = ((const float4*)in)[2 * i + 1];
        half8 h;
        h[0] = (_Float16)a.x; h[1] = (_Float16)a.y; h[2] = (_Float16)a.z; h[3] = (_Float16)a.w;
        h[4] = (_Float16)b.x; h[5] = (_Float16)b.y; h[6] = (_Float16)b.z; h[7] = (_Float16)b.w;
        ((half8*)out)[i] = h;
    }
}

// ---------------------------------------------------------------------------
// Prep 2: W [k][n] fp32 -> WT [n][k] f16 (LDS tile transpose, 64x64 per block).
// ---------------------------------------------------------------------------
#define WTS 68
__global__ __launch_bounds__(256) void cvt_w_t(const float* __restrict__ W,
                                               _Float16* __restrict__ WT) {
    __shared__ _Float16 tile[64 * WTS];
    const int k0 = blockIdx.x * 64;
    const int n0 = blockIdx.y * 64;
    const int t  = threadIdx.x;
    const int r  = t >> 4;          // 0..15
    const int c4 = (t & 15) * 4;    // 0..60
    #pragma unroll
    for (int rr = 0; rr < 64; rr += 16) {
        float4 v = *(const float4*)&W[(size_t)(k0 + rr + r) * DIM + n0 + c4];
        _Float16* dst = &tile[(rr + r) * WTS + c4];
        dst[0] = (_Float16)v.x; dst[1] = (_Float16)v.y;
        dst[2] = (_Float16)v.z; dst[3] = (_Float16)v.w;
    }
    __syncthreads();
    #pragma unroll
    for (int rr = 0; rr < 64; rr += 16) {
        const int n = rr + r;
        half4v h = { tile[(c4 + 0) * WTS + n], tile[(c4 + 1) * WTS + n],
                     tile[(c4 + 2) * WTS + n], tile[(c4 + 3) * WTS + n] };
        *(half4v*)&WT[(size_t)(n0 + n) * DIM + k0 + c4] = h;
    }
}

// ---------------------------------------------------------------------------
// GEMM: C[m][n] = sum_k A[m][k] * B[n][k], all f16 (fp32 accum), C f16 out.
// M=16384, N=1024, K=1024. 128x128 tile, BK=64, 4 waves (2x2), 256 threads.
// Grid (8,128): x = n-tile (fastest) so the 8 blocks sharing an A-panel run
// concurrently and A is fetched once through L3.
// Staging: global_load_lds width=16, linear LDS dest, source chunk
// pre-swizzled by (l&7)^(l>>3); fragment ds_read_b128 applies the same XOR.
// ---------------------------------------------------------------------------
#define GK 64
__global__ __launch_bounds__(256, 2) void gemm_f16t(const _Float16* __restrict__ A,
                                                    const _Float16* __restrict__ B,
                                                    _Float16* __restrict__ C) {
    __shared__ _Float16 As[128 * GK];   // 16 KB
    __shared__ _Float16 Bs[128 * GK];   // 16 KB

    const int m0   = blockIdx.y * 128;
    const int n0   = blockIdx.x * 128;
    const int t    = threadIdx.x;
    const int lane = t & 63;
    const int wv   = t >> 6;
    const int wm   = (wv >> 1) * 64;
    const int wn   = (wv & 1) * 64;
    const int l15  = lane & 15;
    const int quad = lane >> 4;

    const int srow = lane >> 3;             // 0..7 : row within 8-row group
    const int sck  = (lane & 7) ^ srow;     // swizzled source 16B-chunk

    f32x4 acc[4][4] = {};

    for (int k0 = 0; k0 < DIM; k0 += GK) {
        __syncthreads();   // previous iteration's fragment reads done
        #pragma unroll
        for (int j = 0; j < 4; ++j) {
            const int rs = (j * 4 + wv) * 8;   // wave-uniform 8-row group
            GLOAD_LDS16(A + (size_t)(m0 + rs + srow) * DIM + k0 + sck * 8, &As[rs * GK]);
            GLOAD_LDS16(B + (size_t)(n0 + rs + srow) * DIM + k0 + sck * 8, &Bs[rs * GK]);
        }
        __syncthreads();   // compiler drains vmcnt(0) before the barrier

        #pragma unroll
        for (int s = 0; s < 2; ++s) {
            half8 af[4], bf[4];
            #pragma unroll
            for (int i = 0; i < 4; ++i)
                af[i] = *(const half8*)&As[(wm + i * 16 + l15) * GK +
                                           (((s * 4 + quad) ^ (l15 & 7)) * 8)];
            #pragma unroll
            for (int j = 0; j < 4; ++j)
                bf[j] = *(const half8*)&Bs[(wn + j * 16 + l15) * GK +
                                           (((s * 4 + quad) ^ (l15 & 7)) * 8)];
            #pragma unroll
            for (int i = 0; i < 4; ++i)
                #pragma unroll
                for (int j = 0; j < 4; ++j)
                    acc[i][j] = __builtin_amdgcn_mfma_f32_16x16x32_f16(af[i], bf[j], acc[i][j], 0, 0, 0);
        }
    }

    // C/D layout: col = lane&15, row = quad*4 + reg (dtype-independent)
    #pragma unroll
    for (int i = 0; i < 4; ++i) {
        #pragma unroll
        for (int r = 0; r < 4; ++r) {
            _Float16* crow = C + (size_t)(m0 + wm + i * 16 + quad * 4 + r) * DIM + n0 + wn + l15;
            #pragma unroll
            for (int j = 0; j < 4; ++j)
                crow[j * 16] = (_Float16)acc[i][j][r];
        }
    }
}

// ---------------------------------------------------------------------------
// Banded attention v3: 16 queries per block, 4 waves, NO LDS for QK^T.
//  - wave wv owns key cols [16wv, 16wv+16); MFMA fragments loaded straight
//    from global: af = 16B of f16 QT, bf = 32B of fp32 keys cvt in-reg.
//  - softmax: wave 0, via Sl/Wl in LDS (8.4 KB total).
//  - PV: two 8-query register blocks, float4 key loads, float4 out stores.
// ---------------------------------------------------------------------------
#define TQ  16
#define SLD 66

__global__ __launch_bounds__(256) void attn_v3(const _Float16* __restrict__ QT,
                                               const float* __restrict__ Keys,
                                               float* __restrict__ Out) {
    const int blk  = blockIdx.x;
    const int b    = blk & 7;          // batch == XCD (8 XCDs): keys stay L2-local
    const int tile = blk >> 3;
    const int q0   = tile * TQ;
    const int t    = threadIdx.x;
    const int lane = t & 63;
    const int wv   = t >> 6;
    const int l15  = lane & 15;
    const int quad = lane >> 4;

    const int klo = (q0 - WIN) > 0 ? (q0 - WIN) : 0;
    const int khi = (q0 + TQ - 1 + WIN) < (SEQ - 1) ? (q0 + TQ - 1 + WIN) : (SEQ - 1);
    const int nk  = khi - klo + 1;     // <= 56

    const float* keys = Keys + (size_t)b * SEQ * DIM;

    __shared__ float Sl[TQ * SLD];
    __shared__ float Wl[TQ * SLD];

    // ---- QK^T: 32 MFMAs straight from global, no barriers ----
    const _Float16* qrow = QT + ((size_t)b * SEQ + q0 + l15) * DIM + quad * 8;
    int kcol = klo + wv * 16 + l15;
    if (kcol > SEQ - 1) kcol = SEQ - 1;          // pad cols: clamp, masked later
    const float* krow = keys + (size_t)kcol * DIM + quad * 8;

    f32x4 acc_s = {};
    #pragma unroll 4
    for (int dk = 0; dk < DIM; dk += 32) {
        half8 af = *(const half8*)(qrow + dk);
        float4 b0 = *(const float4*)(krow + dk);
        float4 b1 = *(const float4*)(krow + dk + 4);
        half8 bf;
        bf[0] = (_Float16)b0.x; bf[1] = (_Float16)b0.y;
        bf[2] = (_Float16)b0.z; bf[3] = (_Float16)b0.w;
        bf[4] = (_Float16)b1.x; bf[5] = (_Float16)b1.y;
        bf[6] = (_Float16)b1.z; bf[7] = (_Float16)b1.w;
        acc_s = __builtin_amdgcn_mfma_f32_16x16x32_f16(af, bf, acc_s, 0, 0, 0);
    }

    // logits -> Sl with band mask. C layout: col=lane&15 (key), row=quad*4+reg (q).
    #pragma unroll
    for (int r = 0; r < 4; ++r) {
        const int q = quad * 4 + r;
        const int c = wv * 16 + l15;
        const int d = (q0 + q) - (klo + c);
        const bool valid = (c < nk) && ((unsigned)(d + WIN) <= 2u * WIN);
        Sl[q * SLD + c] = valid ? acc_s[r] : -1e30f;
    }
    __syncthreads();

    // softmax: wave 0, 4 lanes per q-row, 16 cols per lane
    if (t < 64) {
        const int q = t >> 2, part = t & 3;
        const float* srow = &Sl[q * SLD + part * 16];
        float*       wrow = &Wl[q * SLD + part * 16];
        float m = -1e30f;
        #pragma unroll
        for (int i = 0; i < 16; ++i) m = fmaxf(m, srow[i]);
        m = fmaxf(m, __shfl_xor(m, 1));
        m = fmaxf(m, __shfl_xor(m, 2));
        float ssum = 0.f;
        #pragma unroll
        for (int i = 0; i < 16; ++i) { float e = expf(srow[i] - m); wrow[i] = e; ssum += e; }
        ssum += __shfl_xor(ssum, 1);
        ssum += __shfl_xor(ssum, 2);
        const float inv = 1.f / ssum;
        #pragma unroll
        for (int i = 0; i < 16; ++i) wrow[i] *= inv;
    }
    __syncthreads();

    // ---- PV: two 8-query register blocks; thread owns d-cols [4t, 4t+4) ----
    const int d4 = t * 4;
    #pragma unroll
    for (int qh = 0; qh < 2; ++qh) {
        float4 accs[8] = {};
        for (int c = 0; c < nk; ++c) {
            const float4 kv = *(const float4*)(keys + (size_t)(klo + c) * DIM + d4);
            #pragma unroll
            for (int q = 0; q < 8; ++q) {
                const float w = Wl[(qh * 8 + q) * SLD + c];   // LDS broadcast
                accs[q].x = fmaf(w, kv.x, accs[q].x);
                accs[q].y = fmaf(w, kv.y, accs[q].y);
                accs[q].z = fmaf(w, kv.z, accs[q].z);
                accs[q].w = fmaf(w, kv.w, accs[q].w);
            }
        }
        #pragma unroll
        for (int q = 0; q < 8; ++q)
            *(float4*)(Out + ((size_t)b * SEQ + q0 + qh * 8 + q) * DIM + d4) = accs[q];
    }
}

// ---------------------------------------------------------------------------
// Fallback GEMM (R3, known good): qt = Q @ W, fp32 in, fp32 out into d_out.
// ---------------------------------------------------------------------------
#define LDK 40
__global__ __launch_bounds__(256) void gemm_qw_f16(const float* __restrict__ Q,
                                                   const float* __restrict__ W,
                                                   float* __restrict__ QT) {
    __shared__ _Float16 Asl[128 * LDK];
    __shared__ _Float16 Bsl[128 * LDK];

    const int m0 = blockIdx.x * 128;
    const int n0 = blockIdx.y * 128;
    const int t  = threadIdx.x;
    const int lane = t & 63;
    const int wv   = t >> 6;
    const int wm   = (wv >> 1) * 64;
    const int wn   = (wv & 1) * 64;
    const int l15  = lane & 15;
    const int quad = lane >> 4;

    const int ar = t >> 1;
    const int ac = (t & 1) * 16;
    const float* Aptr = Q + (size_t)(m0 + ar) * DIM + ac;
    _Float16* AsW = &Asl[ar * LDK + ac];

    const int br = t >> 3;
    const int bc = t & 7;
    const float* Bptr = W + (size_t)br * DIM + n0 + bc;

    f32x4 acc[4][4] = {};

    for (int k0 = 0; k0 < DIM; k0 += 32) {
        float4 a0 = *(const float4*)(Aptr + k0);
        float4 a1 = *(const float4*)(Aptr + k0 + 4);
        float4 a2 = *(const float4*)(Aptr + k0 + 8);
        float4 a3 = *(const float4*)(Aptr + k0 + 12);
        float bv[16];
        #pragma unroll
        for (int j = 0; j < 16; ++j) bv[j] = Bptr[(size_t)k0 * DIM + 8 * j];

        __syncthreads();

        half8 h0, h1;
        h0[0] = (_Float16)a0.x; h0[1] = (_Float16)a0.y; h0[2] = (_Float16)a0.z; h0[3] = (_Float16)a0.w;
        h0[4] = (_Float16)a1.x; h0[5] = (_Float16)a1.y; h0[6] = (_Float16)a1.z; h0[7] = (_Float16)a1.w;
        h1[0] = (_Float16)a2.x; h1[1] = (_Float16)a2.y; h1[2] = (_Float16)a2.z; h1[3] = (_Float16)a2.w;
        h1[4] = (_Float16)a3.x; h1[5] = (_Float16)a3.y; h1[6] = (_Float16)a3.z; h1[7] = (_Float16)a3.w;
        *(half8*)(AsW)     = h0;
        *(half8*)(AsW + 8) = h1;

        #pragma unroll
        for (int j = 0; j < 16; ++j)
            Bsl[(bc + 8 * j) * LDK + br] = (_Float16)bv[j];

        __syncthreads();

        half8 af[4], bf[4];
        #pragma unroll
        for (int i = 0; i < 4; ++i)
            af[i] = *(const half8*)&Asl[(wm + i * 16 + l15) * LDK + quad * 8];
        #pragma unroll
        for (int j = 0; j < 4; ++j)
            bf[j] = *(const half8*)&Bsl[(wn + j * 16 + l15) * LDK + quad * 8];

        #pragma unroll
        for (int i = 0; i < 4; ++i)
            #pragma unroll
            for (int j = 0; j < 4; ++j)
                acc[i][j] = __builtin_amdgcn_mfma_f32_16x16x32_f16(af[i], bf[j], acc[i][j], 0, 0, 0);
    }

    #pragma unroll
    for (int i = 0; i < 4; ++i) {
        const int row0 = m0 + wm + i * 16 + quad * 4;
        #pragma unroll
        for (int r = 0; r < 4; ++r) {
            float* orow = QT + (size_t)(row0 + r) * DIM + n0 + wn + l15;
            #pragma unroll
            for (int j = 0; j < 4; ++j)
                orow[j * 16] = acc[i][j][r];
        }
    }
}

// ---------------------------------------------------------------------------
// Fallback attention (R4): 16 q/block, LDS-staged QK^T, f32 QT in d_out.
// ---------------------------------------------------------------------------
#define KP  64
#define KLD 80
#define QLD 80

__global__ __launch_bounds__(256, 4) void attn_fb(const float* __restrict__ QT,
                                                  const float* __restrict__ Keys,
                                                  float* __restrict__ Out) {
    const int blk  = blockIdx.x;
    const int b    = blk & 7;
    const int tile = blk >> 3;
    const int q0   = tile * TQ;
    const int t    = threadIdx.x;
    const int lane = t & 63;
    const int wv   = t >> 6;
    const int l15  = lane & 15;
    const int quad = lane >> 4;

    const int klo = (q0 - WIN) > 0 ? (q0 - WIN) : 0;
    const int khi = (q0 + TQ - 1 + WIN) < (SEQ - 1) ? (q0 + TQ - 1 + WIN) : (SEQ - 1);
    const int nk  = khi - klo + 1;

    const float* qt   = QT + ((size_t)b * SEQ + q0) * DIM;
    const float* keys = Keys + (size_t)b * SEQ * DIM;

    __shared__ _Float16 Qc[TQ * QLD];
    __shared__ _Float16 Ks[KP * KLD];
    __shared__ float    Sl[TQ * SLD];
    __shared__ float    Wl[TQ * SLD];

    const int qr = t >> 4;
    const int qc = (t & 15) * 4;
    const int kr = t >> 2;
    const int kc = (t & 3) * 4;
    const int krow = (klo + kr) < (SEQ - 1) ? (klo + kr) : (SEQ - 1);

    const float* qsrc = qt + (size_t)qr * DIM + qc;
    const float* ksrc = keys + (size_t)krow * DIM + kc;

    f32x4 acc_s = {};

    for (int d0 = 0; d0 < DIM; d0 += 64) {
        const float4 qv = *(const float4*)(qsrc + d0);
        float4 kv0 = *(const float4*)(ksrc + d0);
        float4 kv1 = *(const float4*)(ksrc + d0 + 16);
        float4 kv2 = *(const float4*)(ksrc + d0 + 32);
        float4 kv3 = *(const float4*)(ksrc + d0 + 48);

        __syncthreads();

        half4v hq = {(_Float16)qv.x, (_Float16)qv.y, (_Float16)qv.z, (_Float16)qv.w};
        *(half4v*)&Qc[qr * QLD + qc] = hq;
        half4v h0 = {(_Float16)kv0.x, (_Float16)kv0.y, (_Float16)kv0.z, (_Float16)kv0.w};
        half4v h1 = {(_Float16)kv1.x, (_Float16)kv1.y, (_Float16)kv1.z, (_Float16)kv1.w};
        half4v h2 = {(_Float16)kv2.x, (_Float16)kv2.y, (_Float16)kv2.z, (_Float16)kv2.w};
        half4v h3 = {(_Float16)kv3.x, (_Float16)kv3.y, (_Float16)kv3.z, (_Float16)kv3.w};
        *(half4v*)&Ks[kr * KLD + kc]      = h0;
        *(half4v*)&Ks[kr * KLD + kc + 16] = h1;
        *(half4v*)&Ks[kr * KLD + kc + 32] = h2;
        *(half4v*)&Ks[kr * KLD + kc + 48] = h3;

        __syncthreads();

        #pragma unroll
        for (int s = 0; s < 2; ++s) {
            half8 af = *(const half8*)&Qc[l15 * QLD + s * 32 + quad * 8];
            half8 bf = *(const half8*)&Ks[(wv * 16 + l15) * KLD + s * 32 + quad * 8];
            acc_s = __builtin_amdgcn_mfma_f32_16x16x32_f16(af, bf, acc_s, 0, 0, 0);
        }
    }

    __syncthreads();
    #pragma unroll
    for (int r = 0; r < 4; ++r) {
        const int q = quad * 4 + r;
        const int c = wv * 16 + l15;
        const int d = (q0 + q) - (klo + c);
        const bool valid = (c < nk) && ((unsigned)(d + WIN) <= 2u * WIN);
        Sl[q * SLD + c] = valid ? acc_s[r] : -1e30f;
    }
    __syncthreads();

    if (t < 64) {
        const int q = t >> 2, part = t & 3;
        const float* srow = &Sl[q * SLD + part * 16];
        float*       wrow = &Wl[q * SLD + part * 16];
        float m = -1e30f;
        #pragma unroll
        for (int i = 0; i < 16; ++i) m = fmaxf(m, srow[i]);
        m = fmaxf(m, __shfl_xor(m, 1));
        m = fmaxf(m, __shfl_xor(m, 2));
        float ssum = 0.f;
        #pragma unroll
        for (int i = 0; i < 16; ++i) { float e = expf(srow[i] - m); wrow[i] = e; ssum += e; }
        ssum += __shfl_xor(ssum, 1);
        ssum += __shfl_xor(ssum, 2);
        const float inv = 1.f / ssum;
        #pragma unroll
        for (int i = 0; i < 16; ++i) wrow[i] *= inv;
    }
    __syncthreads();

    const int d4 = t * 4;
    #pragma unroll
    for (int qh = 0; qh < 2; ++qh) {
        float4 accs[8] = {};
        for (int c = 0; c < nk; ++c) {
            const float4 kv = *(const float4*)(keys + (size_t)(klo + c) * DIM + d4);
            #pragma unroll
            for (int q = 0; q < 8; ++q) {
                const float w = Wl[(qh * 8 + q) * SLD + c];
                accs[q].x = fmaf(w, kv.x, accs[q].x);
                accs[q].y = fmaf(w, kv.y, accs[q].y);
                accs[q].z = fmaf(w, kv.z, accs[q].z);
                accs[q].w = fmaf(w, kv.w, accs[q].w);
            }
        }
        #pragma unroll
        for (int q = 0; q < 8; ++q)
            *(float4*)(Out + ((size_t)b * SEQ + q0 + qh * 8 + q) * DIM + d4) = accs[q];
    }
}

extern "C" void kernel_launch(void* const* d_in, const int* in_sizes, int n_in,
                              void* d_out, int out_size, void* d_ws, size_t ws_size,
                              hipStream_t stream) {
    const float* queries = (const float*)d_in[0];
    const float* keys    = (const float*)d_in[1];
    const float* W       = (const float*)d_in[2];
    // d_in[3] (b_reduce): constant over k within a row -> cancels in softmax.
    float* out = (float*)d_out;

    const size_t qt16_bytes = (size_t)BATCH * SEQ * DIM * sizeof(_Float16);  // 33.5 MB
    const size_t w16_bytes  = (size_t)DIM * DIM * sizeof(_Float16);          //  2.0 MB
    const int nblk = (BATCH * SEQ) / TQ;   // 1024

    if (ws_size >= qt16_bytes + w16_bytes) {
        // Fast path. Q16 lives in d_out (dead until attn overwrites it);
        // QT16 + W16T live in the workspace.
        _Float16* q16  = (_Float16*)d_out;
        _Float16* qt16 = (_Float16*)d_ws;
        _Float16* w16t = (_Float16*)((char*)d_ws + qt16_bytes);

        cvt_q_f16<<<2048, 256, 0, stream>>>(queries, q16);
        cvt_w_t<<<dim3(16, 16), 256, 0, stream>>>(W, w16t);
        gemm_f16t<<<dim3(8, 128), 256, 0, stream>>>(q16, w16t, qt16);
        attn_v3<<<nblk, 256, 0, stream>>>(qt16, keys, out);
    } else {
        // Fallback: R3-style path, fp32 QT through d_out, in-place attn.
        gemm_qw_f16<<<dim3(128, 8), 256, 0, stream>>>(queries, W, out);
        attn_fb<<<nblk, 256, 0, stream>>>(out, keys, out);
    }
}

// Round 5
// 279.028 us; speedup vs baseline: 1.0708x; 1.0708x over previous
//
#include <hip/hip_runtime.h>

// B=8, S=2048, D=1024 banded attention, window +-20.
// out[b,q,:] = softmax_k( q^T W key_k , |q-k|<=20 ) @ keys
// b_reduce: per-q constant on every logit -> cancels in softmax -> unused.
//
// R8: attn_v3 (112us, FETCH 254MB) REVERTED to the R4 LDS-staged structure and
// scaled to TQ=32 (512 thr, 8 waves): window re-read factor 3.5x -> 2.25x.
//   - QK^T: d0-chunks of 64, Q[32][64]+K[80][64] f16 staged in LDS, MFMA.
//   - softmax: 128 threads, 4 lanes/q-row, 20 cols/lane.
//   - PV: single pass over window, all 32 q in registers, float2 weights,
//     fp32 keys from global (L2-hot: same rows staged moments before).
// gemm_f16t / cvt_q_f16 / cvt_w_t unchanged from R7 (ran fine).

#define BATCH 8
#define SEQ   2048
#define DIM   1024
#define WIN   20

typedef _Float16 half8  __attribute__((ext_vector_type(8)));
typedef _Float16 half4v __attribute__((ext_vector_type(4)));
typedef float    f32x4  __attribute__((ext_vector_type(4)));

#define GLOAD_LDS16(gsrc, ldst)                                                        \
    __builtin_amdgcn_global_load_lds(                                                  \
        (const __attribute__((address_space(1))) void*)(gsrc),                         \
        (__attribute__((address_space(3))) void*)(ldst), 16, 0, 0)

// ---------------------------------------------------------------------------
// Prep 1: Q fp32 -> f16, vectorized 8/thread, grid-stride.
// ---------------------------------------------------------------------------
__global__ __launch_bounds__(256) void cvt_q_f16(const float* __restrict__ in,
                                                 _Float16* __restrict__ out) {
    const int n8 = (BATCH * SEQ * DIM) / 8;
    for (int i = blockIdx.x * 256 + threadIdx.x; i < n8; i += gridDim.x * 256) {
        const float4 a = ((const float4*)in)[2 * i];
        const float4 b = ((const float4*)in)[2 * i + 1];
        half8 h;
        h[0] = (_Float16)a.x; h[1] = (_Float16)a.y; h[2] = (_Float16)a.z; h[3] = (_Float16)a.w;
        h[4] = (_Float16)b.x; h[5] = (_Float16)b.y; h[6] = (_Float16)b.z; h[7] = (_Float16)b.w;
        ((half8*)out)[i] = h;
    }
}

// ---------------------------------------------------------------------------
// Prep 2: W [k][n] fp32 -> WT [n][k] f16 (LDS tile transpose, 64x64 per block).
// ---------------------------------------------------------------------------
#define WTS 68
__global__ __launch_bounds__(256) void cvt_w_t(const float* __restrict__ W,
                                               _Float16* __restrict__ WT) {
    __shared__ _Float16 tile[64 * WTS];
    const int k0 = blockIdx.x * 64;
    const int n0 = blockIdx.y * 64;
    const int t  = threadIdx.x;
    const int r  = t >> 4;          // 0..15
    const int c4 = (t & 15) * 4;    // 0..60
    #pragma unroll
    for (int rr = 0; rr < 64; rr += 16) {
        float4 v = *(const float4*)&W[(size_t)(k0 + rr + r) * DIM + n0 + c4];
        _Float16* dst = &tile[(rr + r) * WTS + c4];
        dst[0] = (_Float16)v.x; dst[1] = (_Float16)v.y;
        dst[2] = (_Float16)v.z; dst[3] = (_Float16)v.w;
    }
    __syncthreads();
    #pragma unroll
    for (int rr = 0; rr < 64; rr += 16) {
        const int n = rr + r;
        half4v h = { tile[(c4 + 0) * WTS + n], tile[(c4 + 1) * WTS + n],
                     tile[(c4 + 2) * WTS + n], tile[(c4 + 3) * WTS + n] };
        *(half4v*)&WT[(size_t)(n0 + n) * DIM + k0 + c4] = h;
    }
}

// ---------------------------------------------------------------------------
// GEMM: C[m][n] = sum_k A[m][k] * B[n][k], all f16 (fp32 accum), C f16 out.
// 128x128 tile, BK=64, 4 waves, global_load_lds w=16, XOR-swizzled both sides.
// Grid (8,128) n-fastest: the 8 n-blocks of an m-panel run concurrently.
// ---------------------------------------------------------------------------
#define GK 64
__global__ __launch_bounds__(256, 2) void gemm_f16t(const _Float16* __restrict__ A,
                                                    const _Float16* __restrict__ B,
                                                    _Float16* __restrict__ C) {
    __shared__ _Float16 As[128 * GK];   // 16 KB
    __shared__ _Float16 Bs[128 * GK];   // 16 KB

    const int m0   = blockIdx.y * 128;
    const int n0   = blockIdx.x * 128;
    const int t    = threadIdx.x;
    const int lane = t & 63;
    const int wv   = t >> 6;
    const int wm   = (wv >> 1) * 64;
    const int wn   = (wv & 1) * 64;
    const int l15  = lane & 15;
    const int quad = lane >> 4;

    const int srow = lane >> 3;             // 0..7 : row within 8-row group
    const int sck  = (lane & 7) ^ srow;     // swizzled source 16B-chunk

    f32x4 acc[4][4] = {};

    for (int k0 = 0; k0 < DIM; k0 += GK) {
        __syncthreads();
        #pragma unroll
        for (int j = 0; j < 4; ++j) {
            const int rs = (j * 4 + wv) * 8;
            GLOAD_LDS16(A + (size_t)(m0 + rs + srow) * DIM + k0 + sck * 8, &As[rs * GK]);
            GLOAD_LDS16(B + (size_t)(n0 + rs + srow) * DIM + k0 + sck * 8, &Bs[rs * GK]);
        }
        __syncthreads();

        #pragma unroll
        for (int s = 0; s < 2; ++s) {
            half8 af[4], bf[4];
            #pragma unroll
            for (int i = 0; i < 4; ++i)
                af[i] = *(const half8*)&As[(wm + i * 16 + l15) * GK +
                                           (((s * 4 + quad) ^ (l15 & 7)) * 8)];
            #pragma unroll
            for (int j = 0; j < 4; ++j)
                bf[j] = *(const half8*)&Bs[(wn + j * 16 + l15) * GK +
                                           (((s * 4 + quad) ^ (l15 & 7)) * 8)];
            #pragma unroll
            for (int i = 0; i < 4; ++i)
                #pragma unroll
                for (int j = 0; j < 4; ++j)
                    acc[i][j] = __builtin_amdgcn_mfma_f32_16x16x32_f16(af[i], bf[j], acc[i][j], 0, 0, 0);
        }
    }

    #pragma unroll
    for (int i = 0; i < 4; ++i) {
        #pragma unroll
        for (int r = 0; r < 4; ++r) {
            _Float16* crow = C + (size_t)(m0 + wm + i * 16 + quad * 4 + r) * DIM + n0 + wn + l15;
            #pragma unroll
            for (int j = 0; j < 4; ++j)
                crow[j * 16] = (_Float16)acc[i][j][r];
        }
    }
}

// ---------------------------------------------------------------------------
// Banded attention v4: 32 queries/block, 512 threads (8 waves).
// Window: klo..khi, nk <= 72, padded to 80 MFMA cols (5 k-tiles of 16).
// Wave wv: q-tile qt = wv>>2; k-tile kt = wv&3 (+ kt=4 for wv&3==0).
// ---------------------------------------------------------------------------
#define TQV  32
#define KPV  80
#define KLD2 80   // f16 stride (160 B)
#define QLD2 80
#define SLD2 84   // f32 stride for Sl/Wl

__global__ __launch_bounds__(512, 4) void attn_v4(const _Float16* __restrict__ QT,
                                                  const float* __restrict__ Keys,
                                                  float* __restrict__ Out) {
    const int blk  = blockIdx.x;
    const int b    = blk & 7;          // batch == XCD: keys L2-local
    const int tile = blk >> 3;         // 0..63
    const int q0   = tile * TQV;
    const int t    = threadIdx.x;
    const int lane = t & 63;
    const int wv   = t >> 6;           // 0..7
    const int l15  = lane & 15;
    const int quad = lane >> 4;

    const int klo = (q0 - WIN) > 0 ? (q0 - WIN) : 0;
    const int khi = (q0 + TQV - 1 + WIN) < (SEQ - 1) ? (q0 + TQV - 1 + WIN) : (SEQ - 1);
    const int nk  = khi - klo + 1;     // <= 72

    const float* keys = Keys + (size_t)b * SEQ * DIM;

    __shared__ _Float16 Qc[TQV * QLD2];   //  5.0 KB
    __shared__ _Float16 Ks[KPV * KLD2];   // 12.8 KB
    __shared__ float    Sl[TQV * SLD2];   // 10.8 KB
    __shared__ float    Wl[TQV * SLD2];   // 10.8 KB

    // staging assignments
    const int qr = t >> 4;             // 0..31 (q row)
    const int qc = (t & 15) * 4;       // 0..60
    const int kr = t >> 3;             // 0..63 (key row, first batch)
    const int kc = (t & 7) * 8;        // 0,8,..,56
    const int krow0 = (klo + kr) < (SEQ - 1) ? (klo + kr) : (SEQ - 1);
    const int kr2   = 64 + (t >> 3);   // 64..79 (second batch, t<128)
    const int krow2 = (klo + kr2) < (SEQ - 1) ? (klo + kr2) : (SEQ - 1);

    const _Float16* qsrc = QT + ((size_t)b * SEQ + q0 + qr) * DIM + qc;
    const float*    ksrc0 = keys + (size_t)krow0 * DIM + kc;
    const float*    ksrc2 = keys + (size_t)krow2 * DIM + kc;

    const int qt_w = wv >> 2;          // 0..1
    const int kt_a = wv & 3;           // 0..3
    const bool two = (kt_a == 0);      // this wave also does kt=4

    f32x4 acc0 = {}, acc1 = {};

    for (int d0 = 0; d0 < DIM; d0 += 64) {
        half4v hq = *(const half4v*)(qsrc + d0);
        float4 kv0 = *(const float4*)(ksrc0 + d0);
        float4 kv1 = *(const float4*)(ksrc0 + d0 + 4);
        float4 kv2, kv3;
        if (t < 128) {
            kv2 = *(const float4*)(ksrc2 + d0);
            kv3 = *(const float4*)(ksrc2 + d0 + 4);
        }

        __syncthreads();   // previous iteration's fragment reads done

        *(half4v*)&Qc[qr * QLD2 + qc] = hq;
        half8 h0;
        h0[0] = (_Float16)kv0.x; h0[1] = (_Float16)kv0.y;
        h0[2] = (_Float16)kv0.z; h0[3] = (_Float16)kv0.w;
        h0[4] = (_Float16)kv1.x; h0[5] = (_Float16)kv1.y;
        h0[6] = (_Float16)kv1.z; h0[7] = (_Float16)kv1.w;
        *(half8*)&Ks[kr * KLD2 + kc] = h0;
        if (t < 128) {
            half8 h2;
            h2[0] = (_Float16)kv2.x; h2[1] = (_Float16)kv2.y;
            h2[2] = (_Float16)kv2.z; h2[3] = (_Float16)kv2.w;
            h2[4] = (_Float16)kv3.x; h2[5] = (_Float16)kv3.y;
            h2[6] = (_Float16)kv3.z; h2[7] = (_Float16)kv3.w;
            *(half8*)&Ks[kr2 * KLD2 + kc] = h2;
        }

        __syncthreads();

        #pragma unroll
        for (int s = 0; s < 2; ++s) {
            half8 af = *(const half8*)&Qc[(qt_w * 16 + l15) * QLD2 + s * 32 + quad * 8];
            half8 bf0 = *(const half8*)&Ks[(kt_a * 16 + l15) * KLD2 + s * 32 + quad * 8];
            acc0 = __builtin_amdgcn_mfma_f32_16x16x32_f16(af, bf0, acc0, 0, 0, 0);
            if (two) {
                half8 bf1 = *(const half8*)&Ks[(4 * 16 + l15) * KLD2 + s * 32 + quad * 8];
                acc1 = __builtin_amdgcn_mfma_f32_16x16x32_f16(af, bf1, acc1, 0, 0, 0);
            }
        }
    }

    // logits -> Sl with band mask. C layout: col=l15 (key), row=quad*4+r (q).
    __syncthreads();
    #pragma unroll
    for (int r = 0; r < 4; ++r) {
        const int q = qt_w * 16 + quad * 4 + r;
        {
            const int c = kt_a * 16 + l15;
            const int d = (q0 + q) - (klo + c);
            const bool valid = (c < nk) && ((unsigned)(d + WIN) <= 2u * WIN);
            Sl[q * SLD2 + c] = valid ? acc0[r] : -1e30f;
        }
        if (two) {
            const int c = 64 + l15;
            const int d = (q0 + q) - (klo + c);
            const bool valid = (c < nk) && ((unsigned)(d + WIN) <= 2u * WIN);
            Sl[q * SLD2 + c] = valid ? acc1[r] : -1e30f;
        }
    }
    __syncthreads();

    // softmax: 128 threads, 4 lanes per q-row, 20 cols per lane (80 padded)
    if (t < 128) {
        const int q = t >> 2, part = t & 3;
        const float* srow = &Sl[q * SLD2 + part * 20];
        float*       wrow = &Wl[q * SLD2 + part * 20];
        float m = -1e30f;
        #pragma unroll
        for (int i = 0; i < 20; ++i) m = fmaxf(m, srow[i]);
        m = fmaxf(m, __shfl_xor(m, 1));
        m = fmaxf(m, __shfl_xor(m, 2));
        float ssum = 0.f;
        #pragma unroll
        for (int i = 0; i < 20; ++i) { float e = expf(srow[i] - m); wrow[i] = e; ssum += e; }
        ssum += __shfl_xor(ssum, 1);
        ssum += __shfl_xor(ssum, 2);
        const float inv = 1.f / ssum;
        #pragma unroll
        for (int i = 0; i < 20; ++i) wrow[i] *= inv;
    }
    __syncthreads();

    // PV: thread t owns d-cols {t, t+512}; single pass, fp32 keys (L2-hot).
    float2 accs[TQV] = {};
    int c = 0;
    for (; c + 1 < nk; c += 2) {
        const float* ka = keys + (size_t)(klo + c) * DIM;
        const float* kb = keys + (size_t)(klo + c + 1) * DIM;
        const float a0 = ka[t], a1 = ka[t + 512];
        const float b0 = kb[t], b1 = kb[t + 512];
        #pragma unroll
        for (int q = 0; q < TQV; ++q) {
            const float2 w = *(const float2*)&Wl[q * SLD2 + c];   // broadcast
            accs[q].x = fmaf(w.x, a0, fmaf(w.y, b0, accs[q].x));
            accs[q].y = fmaf(w.x, a1, fmaf(w.y, b1, accs[q].y));
        }
    }
    if (c < nk) {
        const float* ka = keys + (size_t)(klo + c) * DIM;
        const float a0 = ka[t], a1 = ka[t + 512];
        #pragma unroll
        for (int q = 0; q < TQV; ++q) {
            const float w = Wl[q * SLD2 + c];
            accs[q].x = fmaf(w, a0, accs[q].x);
            accs[q].y = fmaf(w, a1, accs[q].y);
        }
    }
    #pragma unroll
    for (int q = 0; q < TQV; ++q) {
        float* orow = Out + ((size_t)b * SEQ + q0 + q) * DIM;
        orow[t]       = accs[q].x;
        orow[t + 512] = accs[q].y;
    }
}

// ---------------------------------------------------------------------------
// Fallback GEMM (R3, known good): qt = Q @ W, fp32 in, fp32 out into d_out.
// ---------------------------------------------------------------------------
#define LDK 40
__global__ __launch_bounds__(256) void gemm_qw_f16(const float* __restrict__ Q,
                                                   const float* __restrict__ W,
                                                   float* __restrict__ QT) {
    __shared__ _Float16 Asl[128 * LDK];
    __shared__ _Float16 Bsl[128 * LDK];

    const int m0 = blockIdx.x * 128;
    const int n0 = blockIdx.y * 128;
    const int t  = threadIdx.x;
    const int lane = t & 63;
    const int wv   = t >> 6;
    const int wm   = (wv >> 1) * 64;
    const int wn   = (wv & 1) * 64;
    const int l15  = lane & 15;
    const int quad = lane >> 4;

    const int ar = t >> 1;
    const int ac = (t & 1) * 16;
    const float* Aptr = Q + (size_t)(m0 + ar) * DIM + ac;
    _Float16* AsW = &Asl[ar * LDK + ac];

    const int br = t >> 3;
    const int bc = t & 7;
    const float* Bptr = W + (size_t)br * DIM + n0 + bc;

    f32x4 acc[4][4] = {};

    for (int k0 = 0; k0 < DIM; k0 += 32) {
        float4 a0 = *(const float4*)(Aptr + k0);
        float4 a1 = *(const float4*)(Aptr + k0 + 4);
        float4 a2 = *(const float4*)(Aptr + k0 + 8);
        float4 a3 = *(const float4*)(Aptr + k0 + 12);
        float bv[16];
        #pragma unroll
        for (int j = 0; j < 16; ++j) bv[j] = Bptr[(size_t)k0 * DIM + 8 * j];

        __syncthreads();

        half8 h0, h1;
        h0[0] = (_Float16)a0.x; h0[1] = (_Float16)a0.y; h0[2] = (_Float16)a0.z; h0[3] = (_Float16)a0.w;
        h0[4] = (_Float16)a1.x; h0[5] = (_Float16)a1.y; h0[6] = (_Float16)a1.z; h0[7] = (_Float16)a1.w;
        h1[0] = (_Float16)a2.x; h1[1] = (_Float16)a2.y; h1[2] = (_Float16)a2.z; h1[3] = (_Float16)a2.w;
        h1[4] = (_Float16)a3.x; h1[5] = (_Float16)a3.y; h1[6] = (_Float16)a3.z; h1[7] = (_Float16)a3.w;
        *(half8*)(AsW)     = h0;
        *(half8*)(AsW + 8) = h1;

        #pragma unroll
        for (int j = 0; j < 16; ++j)
            Bsl[(bc + 8 * j) * LDK + br] = (_Float16)bv[j];

        __syncthreads();

        half8 af[4], bf[4];
        #pragma unroll
        for (int i = 0; i < 4; ++i)
            af[i] = *(const half8*)&Asl[(wm + i * 16 + l15) * LDK + quad * 8];
        #pragma unroll
        for (int j = 0; j < 4; ++j)
            bf[j] = *(const half8*)&Bsl[(wn + j * 16 + l15) * LDK + quad * 8];

        #pragma unroll
        for (int i = 0; i < 4; ++i)
            #pragma unroll
            for (int j = 0; j < 4; ++j)
                acc[i][j] = __builtin_amdgcn_mfma_f32_16x16x32_f16(af[i], bf[j], acc[i][j], 0, 0, 0);
    }

    #pragma unroll
    for (int i = 0; i < 4; ++i) {
        const int row0 = m0 + wm + i * 16 + quad * 4;
        #pragma unroll
        for (int r = 0; r < 4; ++r) {
            float* orow = QT + (size_t)(row0 + r) * DIM + n0 + wn + l15;
            #pragma unroll
            for (int j = 0; j < 4; ++j)
                orow[j * 16] = acc[i][j][r];
        }
    }
}

// ---------------------------------------------------------------------------
// Fallback attention (R4-verified): 16 q/block, LDS-staged, f32 QT in d_out.
// ---------------------------------------------------------------------------
#define TQ  16
#define KP  64
#define KLD 80
#define QLD 80
#define SLD 66

__global__ __launch_bounds__(256, 4) void attn_fb(const float* __restrict__ QT,
                                                  const float* __restrict__ Keys,
                                                  float* __restrict__ Out) {
    const int blk  = blockIdx.x;
    const int b    = blk & 7;
    const int tile = blk >> 3;
    const int q0   = tile * TQ;
    const int t    = threadIdx.x;
    const int lane = t & 63;
    const int wv   = t >> 6;
    const int l15  = lane & 15;
    const int quad = lane >> 4;

    const int klo = (q0 - WIN) > 0 ? (q0 - WIN) : 0;
    const int khi = (q0 + TQ - 1 + WIN) < (SEQ - 1) ? (q0 + TQ - 1 + WIN) : (SEQ - 1);
    const int nk  = khi - klo + 1;

    const float* qt   = QT + ((size_t)b * SEQ + q0) * DIM;
    const float* keys = Keys + (size_t)b * SEQ * DIM;

    __shared__ _Float16 Qc[TQ * QLD];
    __shared__ _Float16 Ks[KP * KLD];
    __shared__ float    Sl[TQ * SLD];
    __shared__ float    Wl[TQ * SLD];

    const int qr = t >> 4;
    const int qc = (t & 15) * 4;
    const int kr = t >> 2;
    const int kc = (t & 3) * 4;
    const int krow = (klo + kr) < (SEQ - 1) ? (klo + kr) : (SEQ - 1);

    const float* qsrc = qt + (size_t)qr * DIM + qc;
    const float* ksrc = keys + (size_t)krow * DIM + kc;

    f32x4 acc_s = {};

    for (int d0 = 0; d0 < DIM; d0 += 64) {
        const float4 qv = *(const float4*)(qsrc + d0);
        float4 kv0 = *(const float4*)(ksrc + d0);
        float4 kv1 = *(const float4*)(ksrc + d0 + 16);
        float4 kv2 = *(const float4*)(ksrc + d0 + 32);
        float4 kv3 = *(const float4*)(ksrc + d0 + 48);

        __syncthreads();

        half4v hq = {(_Float16)qv.x, (_Float16)qv.y, (_Float16)qv.z, (_Float16)qv.w};
        *(half4v*)&Qc[qr * QLD + qc] = hq;
        half4v h0 = {(_Float16)kv0.x, (_Float16)kv0.y, (_Float16)kv0.z, (_Float16)kv0.w};
        half4v h1 = {(_Float16)kv1.x, (_Float16)kv1.y, (_Float16)kv1.z, (_Float16)kv1.w};
        half4v h2 = {(_Float16)kv2.x, (_Float16)kv2.y, (_Float16)kv2.z, (_Float16)kv2.w};
        half4v h3 = {(_Float16)kv3.x, (_Float16)kv3.y, (_Float16)kv3.z, (_Float16)kv3.w};
        *(half4v*)&Ks[kr * KLD + kc]      = h0;
        *(half4v*)&Ks[kr * KLD + kc + 16] = h1;
        *(half4v*)&Ks[kr * KLD + kc + 32] = h2;
        *(half4v*)&Ks[kr * KLD + kc + 48] = h3;

        __syncthreads();

        #pragma unroll
        for (int s = 0; s < 2; ++s) {
            half8 af = *(const half8*)&Qc[l15 * QLD + s * 32 + quad * 8];
            half8 bf = *(const half8*)&Ks[(wv * 16 + l15) * KLD + s * 32 + quad * 8];
            acc_s = __builtin_amdgcn_mfma_f32_16x16x32_f16(af, bf, acc_s, 0, 0, 0);
        }
    }

    __syncthreads();
    #pragma unroll
    for (int r = 0; r < 4; ++r) {
        const int q = quad * 4 + r;
        const int c = wv * 16 + l15;
        const int d = (q0 + q) - (klo + c);
        const bool valid = (c < nk) && ((unsigned)(d + WIN) <= 2u * WIN);
        Sl[q * SLD + c] = valid ? acc_s[r] : -1e30f;
    }
    __syncthreads();

    if (t < 64) {
        const int q = t >> 2, part = t & 3;
        const float* srow = &Sl[q * SLD + part * 16];
        float*       wrow = &Wl[q * SLD + part * 16];
        float m = -1e30f;
        #pragma unroll
        for (int i = 0; i < 16; ++i) m = fmaxf(m, srow[i]);
        m = fmaxf(m, __shfl_xor(m, 1));
        m = fmaxf(m, __shfl_xor(m, 2));
        float ssum = 0.f;
        #pragma unroll
        for (int i = 0; i < 16; ++i) { float e = expf(srow[i] - m); wrow[i] = e; ssum += e; }
        ssum += __shfl_xor(ssum, 1);
        ssum += __shfl_xor(ssum, 2);
        const float inv = 1.f / ssum;
        #pragma unroll
        for (int i = 0; i < 16; ++i) wrow[i] *= inv;
    }
    __syncthreads();

    float accs[TQ][4] = {};
    for (int c = 0; c < nk; ++c) {
        const float* krow2 = keys + (size_t)(klo + c) * DIM;
        const float k0 = krow2[t], k1 = krow2[t + 256], k2 = krow2[t + 512], k3 = krow2[t + 768];
        #pragma unroll
        for (int q = 0; q < TQ; ++q) {
            const float w = Wl[q * SLD + c];
            accs[q][0] = fmaf(w, k0, accs[q][0]);
            accs[q][1] = fmaf(w, k1, accs[q][1]);
            accs[q][2] = fmaf(w, k2, accs[q][2]);
            accs[q][3] = fmaf(w, k3, accs[q][3]);
        }
    }
    #pragma unroll
    for (int q = 0; q < TQ; ++q) {
        float* orow = Out + ((size_t)b * SEQ + q0 + q) * DIM;
        orow[t]       = accs[q][0];
        orow[t + 256] = accs[q][1];
        orow[t + 512] = accs[q][2];
        orow[t + 768] = accs[q][3];
    }
}

extern "C" void kernel_launch(void* const* d_in, const int* in_sizes, int n_in,
                              void* d_out, int out_size, void* d_ws, size_t ws_size,
                              hipStream_t stream) {
    const float* queries = (const float*)d_in[0];
    const float* keys    = (const float*)d_in[1];
    const float* W       = (const float*)d_in[2];
    // d_in[3] (b_reduce): constant over k within a row -> cancels in softmax.
    float* out = (float*)d_out;

    const size_t qt16_bytes = (size_t)BATCH * SEQ * DIM * sizeof(_Float16);  // 33.5 MB
    const size_t w16_bytes  = (size_t)DIM * DIM * sizeof(_Float16);          //  2.0 MB

    if (ws_size >= qt16_bytes + w16_bytes) {
        // Fast path. Q16 lives in d_out (dead until attn overwrites it);
        // QT16 + W16T live in the workspace.
        _Float16* q16  = (_Float16*)d_out;
        _Float16* qt16 = (_Float16*)d_ws;
        _Float16* w16t = (_Float16*)((char*)d_ws + qt16_bytes);

        cvt_q_f16<<<2048, 256, 0, stream>>>(queries, q16);
        cvt_w_t<<<dim3(16, 16), 256, 0, stream>>>(W, w16t);
        gemm_f16t<<<dim3(8, 128), 256, 0, stream>>>(q16, w16t, qt16);
        const int nblk = (BATCH * SEQ) / TQV;   // 512
        attn_v4<<<nblk, 512, 0, stream>>>(qt16, keys, out);
    } else {
        // Fallback: R3-style path, fp32 QT through d_out, in-place attn.
        gemm_qw_f16<<<dim3(128, 8), 256, 0, stream>>>(queries, W, out);
        const int nblk = (BATCH * SEQ) / TQ;    // 1024
        attn_fb<<<nblk, 256, 0, stream>>>(out, keys, out);
    }
}

// Round 6
// 251.229 us; speedup vs baseline: 1.1893x; 1.1107x over previous
//
#include <hip/hip_runtime.h>

// B=8, S=2048, D=1024 banded attention, window +-20.
// out[b,q,:] = softmax_k( q^T W key_k , |q-k|<=20 ) @ keys
// b_reduce: per-q constant on every logit -> cancels in softmax -> unused.
//
// R9: attn_v5 = attn_v4 with PV rewritten as MFMA.
//   R8 post-mortem: v4's PV issued 32 ds_read_b64 weight-broadcasts per c-pair
//   per thread (~18K LDS wave-insts/CU ~ 60us of LDS issue serialization).
//   v5: softmax -> Pl[32][104] f16 (zero-padded to c=96); per 64-d chunk
//   re-stage keys f16 into Ks (same layout as QK^T) and compute
//   out[q][d] = sum_c Pl[q][c]*K[c][d] with 16x16x32 MFMA (3 K-steps, c<96).
//   B-fragment = key column, read as 8x ds_read_u16 (4-way conflict, ~1.6x).
// gemm_f16t / cvt_q_f16 / cvt_w_t / fallbacks unchanged.

#define BATCH 8
#define SEQ   2048
#define DIM   1024
#define WIN   20

typedef _Float16 half8  __attribute__((ext_vector_type(8)));
typedef _Float16 half4v __attribute__((ext_vector_type(4)));
typedef float    f32x4  __attribute__((ext_vector_type(4)));

#define GLOAD_LDS16(gsrc, ldst)                                                        \
    __builtin_amdgcn_global_load_lds(                                                  \
        (const __attribute__((address_space(1))) void*)(gsrc),                         \
        (__attribute__((address_space(3))) void*)(ldst), 16, 0, 0)

// ---------------------------------------------------------------------------
// Prep 1: Q fp32 -> f16, vectorized 8/thread, grid-stride.
// ---------------------------------------------------------------------------
__global__ __launch_bounds__(256) void cvt_q_f16(const float* __restrict__ in,
                                                 _Float16* __restrict__ out) {
    const int n8 = (BATCH * SEQ * DIM) / 8;
    for (int i = blockIdx.x * 256 + threadIdx.x; i < n8; i += gridDim.x * 256) {
        const float4 a = ((const float4*)in)[2 * i];
        const float4 b = ((const float4*)in)[2 * i + 1];
        half8 h;
        h[0] = (_Float16)a.x; h[1] = (_Float16)a.y; h[2] = (_Float16)a.z; h[3] = (_Float16)a.w;
        h[4] = (_Float16)b.x; h[5] = (_Float16)b.y; h[6] = (_Float16)b.z; h[7] = (_Float16)b.w;
        ((half8*)out)[i] = h;
    }
}

// ---------------------------------------------------------------------------
// Prep 2: W [k][n] fp32 -> WT [n][k] f16 (LDS tile transpose, 64x64 per block).
// ---------------------------------------------------------------------------
#define WTS 68
__global__ __launch_bounds__(256) void cvt_w_t(const float* __restrict__ W,
                                               _Float16* __restrict__ WT) {
    __shared__ _Float16 tile[64 * WTS];
    const int k0 = blockIdx.x * 64;
    const int n0 = blockIdx.y * 64;
    const int t  = threadIdx.x;
    const int r  = t >> 4;          // 0..15
    const int c4 = (t & 15) * 4;    // 0..60
    #pragma unroll
    for (int rr = 0; rr < 64; rr += 16) {
        float4 v = *(const float4*)&W[(size_t)(k0 + rr + r) * DIM + n0 + c4];
        _Float16* dst = &tile[(rr + r) * WTS + c4];
        dst[0] = (_Float16)v.x; dst[1] = (_Float16)v.y;
        dst[2] = (_Float16)v.z; dst[3] = (_Float16)v.w;
    }
    __syncthreads();
    #pragma unroll
    for (int rr = 0; rr < 64; rr += 16) {
        const int n = rr + r;
        half4v h = { tile[(c4 + 0) * WTS + n], tile[(c4 + 1) * WTS + n],
                     tile[(c4 + 2) * WTS + n], tile[(c4 + 3) * WTS + n] };
        *(half4v*)&WT[(size_t)(n0 + n) * DIM + k0 + c4] = h;
    }
}

// ---------------------------------------------------------------------------
// GEMM: C[m][n] = sum_k A[m][k] * B[n][k], all f16 (fp32 accum), C f16 out.
// 128x128 tile, BK=64, 4 waves, global_load_lds w=16, XOR-swizzled both sides.
// ---------------------------------------------------------------------------
#define GK 64
__global__ __launch_bounds__(256, 2) void gemm_f16t(const _Float16* __restrict__ A,
                                                    const _Float16* __restrict__ B,
                                                    _Float16* __restrict__ C) {
    __shared__ _Float16 As[128 * GK];   // 16 KB
    __shared__ _Float16 Bs[128 * GK];   // 16 KB

    const int m0   = blockIdx.y * 128;
    const int n0   = blockIdx.x * 128;
    const int t    = threadIdx.x;
    const int lane = t & 63;
    const int wv   = t >> 6;
    const int wm   = (wv >> 1) * 64;
    const int wn   = (wv & 1) * 64;
    const int l15  = lane & 15;
    const int quad = lane >> 4;

    const int srow = lane >> 3;             // 0..7 : row within 8-row group
    const int sck  = (lane & 7) ^ srow;     // swizzled source 16B-chunk

    f32x4 acc[4][4] = {};

    for (int k0 = 0; k0 < DIM; k0 += GK) {
        __syncthreads();
        #pragma unroll
        for (int j = 0; j < 4; ++j) {
            const int rs = (j * 4 + wv) * 8;
            GLOAD_LDS16(A + (size_t)(m0 + rs + srow) * DIM + k0 + sck * 8, &As[rs * GK]);
            GLOAD_LDS16(B + (size_t)(n0 + rs + srow) * DIM + k0 + sck * 8, &Bs[rs * GK]);
        }
        __syncthreads();

        #pragma unroll
        for (int s = 0; s < 2; ++s) {
            half8 af[4], bf[4];
            #pragma unroll
            for (int i = 0; i < 4; ++i)
                af[i] = *(const half8*)&As[(wm + i * 16 + l15) * GK +
                                           (((s * 4 + quad) ^ (l15 & 7)) * 8)];
            #pragma unroll
            for (int j = 0; j < 4; ++j)
                bf[j] = *(const half8*)&Bs[(wn + j * 16 + l15) * GK +
                                           (((s * 4 + quad) ^ (l15 & 7)) * 8)];
            #pragma unroll
            for (int i = 0; i < 4; ++i)
                #pragma unroll
                for (int j = 0; j < 4; ++j)
                    acc[i][j] = __builtin_amdgcn_mfma_f32_16x16x32_f16(af[i], bf[j], acc[i][j], 0, 0, 0);
        }
    }

    #pragma unroll
    for (int i = 0; i < 4; ++i) {
        #pragma unroll
        for (int r = 0; r < 4; ++r) {
            _Float16* crow = C + (size_t)(m0 + wm + i * 16 + quad * 4 + r) * DIM + n0 + wn + l15;
            #pragma unroll
            for (int j = 0; j < 4; ++j)
                crow[j * 16] = (_Float16)acc[i][j][r];
        }
    }
}

// ---------------------------------------------------------------------------
// Banded attention v5: 32 queries/block, 512 threads (8 waves).
// Pass 1 (QK^T) as v4. Softmax -> Pl f16. Pass 2 (PV) via MFMA per 64-d chunk.
// ---------------------------------------------------------------------------
#define TQV  32
#define KSR  96   // Ks rows (c), padded for K=96 MFMA reduction
#define KLD2 80   // Ks stride (f16)
#define QLD2 80
#define SLD2 84   // Sl stride (f32)
#define PLD  104  // Pl stride (f16): 208 B rows -> near-conflict-free af reads

__global__ __launch_bounds__(512, 4) void attn_v5(const _Float16* __restrict__ QT,
                                                  const float* __restrict__ Keys,
                                                  float* __restrict__ Out) {
    const int blk  = blockIdx.x;
    const int b    = blk & 7;          // batch == XCD: keys L2-local
    const int tile = blk >> 3;         // 0..63
    const int q0   = tile * TQV;
    const int t    = threadIdx.x;
    const int lane = t & 63;
    const int wv   = t >> 6;           // 0..7
    const int l15  = lane & 15;
    const int quad = lane >> 4;

    const int klo = (q0 - WIN) > 0 ? (q0 - WIN) : 0;
    const int khi = (q0 + TQV - 1 + WIN) < (SEQ - 1) ? (q0 + TQV - 1 + WIN) : (SEQ - 1);
    const int nk  = khi - klo + 1;     // <= 72

    const float* keys = Keys + (size_t)b * SEQ * DIM;

    __shared__ _Float16 Qc[TQV * QLD2];   //  5.0 KB
    __shared__ _Float16 Ks[KSR * KLD2];   // 15.4 KB
    __shared__ float    Sl[TQV * SLD2];   // 10.8 KB
    __shared__ _Float16 Pl[TQV * PLD];    //  6.7 KB

    // ---- Pass 1: QK^T (identical structure to v4) ----
    const int qr = t >> 4;             // 0..31 (q row)
    const int qc = (t & 15) * 4;       // 0..60
    const int kr = t >> 3;             // 0..63 (key row, first batch)
    const int kc = (t & 7) * 8;        // 0,8,..,56
    const int krow0 = (klo + kr) < (SEQ - 1) ? (klo + kr) : (SEQ - 1);
    const int kr2   = 64 + (t >> 3);   // 64..79 (second batch, t<128)
    const int krow2 = (klo + kr2) < (SEQ - 1) ? (klo + kr2) : (SEQ - 1);

    const _Float16* qsrc  = QT + ((size_t)b * SEQ + q0 + qr) * DIM + qc;
    const float*    ksrc0 = keys + (size_t)krow0 * DIM + kc;
    const float*    ksrc2 = keys + (size_t)krow2 * DIM + kc;

    const int qt_w = wv >> 2;          // 0..1
    const int kt_a = wv & 3;           // 0..3
    const bool two = (kt_a == 0);      // this wave also does kt=4

    f32x4 acc0 = {}, acc1 = {};

    for (int d0 = 0; d0 < DIM; d0 += 64) {
        half4v hq = *(const half4v*)(qsrc + d0);
        float4 kv0 = *(const float4*)(ksrc0 + d0);
        float4 kv1 = *(const float4*)(ksrc0 + d0 + 4);
        float4 kv2, kv3;
        if (t < 128) {
            kv2 = *(const float4*)(ksrc2 + d0);
            kv3 = *(const float4*)(ksrc2 + d0 + 4);
        }

        __syncthreads();   // previous iteration's fragment reads done

        *(half4v*)&Qc[qr * QLD2 + qc] = hq;
        half8 h0;
        h0[0] = (_Float16)kv0.x; h0[1] = (_Float16)kv0.y;
        h0[2] = (_Float16)kv0.z; h0[3] = (_Float16)kv0.w;
        h0[4] = (_Float16)kv1.x; h0[5] = (_Float16)kv1.y;
        h0[6] = (_Float16)kv1.z; h0[7] = (_Float16)kv1.w;
        *(half8*)&Ks[kr * KLD2 + kc] = h0;
        if (t < 128) {
            half8 h2;
            h2[0] = (_Float16)kv2.x; h2[1] = (_Float16)kv2.y;
            h2[2] = (_Float16)kv2.z; h2[3] = (_Float16)kv2.w;
            h2[4] = (_Float16)kv3.x; h2[5] = (_Float16)kv3.y;
            h2[6] = (_Float16)kv3.z; h2[7] = (_Float16)kv3.w;
            *(half8*)&Ks[kr2 * KLD2 + kc] = h2;
        }

        __syncthreads();

        #pragma unroll
        for (int s = 0; s < 2; ++s) {
            half8 af = *(const half8*)&Qc[(qt_w * 16 + l15) * QLD2 + s * 32 + quad * 8];
            half8 bf0 = *(const half8*)&Ks[(kt_a * 16 + l15) * KLD2 + s * 32 + quad * 8];
            acc0 = __builtin_amdgcn_mfma_f32_16x16x32_f16(af, bf0, acc0, 0, 0, 0);
            if (two) {
                half8 bf1 = *(const half8*)&Ks[(4 * 16 + l15) * KLD2 + s * 32 + quad * 8];
                acc1 = __builtin_amdgcn_mfma_f32_16x16x32_f16(af, bf1, acc1, 0, 0, 0);
            }
        }
    }

    // logits -> Sl with band mask. C layout: col=l15 (key), row=quad*4+r (q).
    __syncthreads();
    #pragma unroll
    for (int r = 0; r < 4; ++r) {
        const int q = qt_w * 16 + quad * 4 + r;
        {
            const int c = kt_a * 16 + l15;
            const int d = (q0 + q) - (klo + c);
            const bool valid = (c < nk) && ((unsigned)(d + WIN) <= 2u * WIN);
            Sl[q * SLD2 + c] = valid ? acc0[r] : -1e30f;
        }
        if (two) {
            const int c = 64 + l15;
            const int d = (q0 + q) - (klo + c);
            const bool valid = (c < nk) && ((unsigned)(d + WIN) <= 2u * WIN);
            Sl[q * SLD2 + c] = valid ? acc1[r] : -1e30f;
        }
    }
    __syncthreads();

    // softmax: 128 threads, 4 lanes/q-row, 20 cols/lane; weights -> Pl f16.
    if (t < 128) {
        const int q = t >> 2, part = t & 3;
        const float* srow = &Sl[q * SLD2 + part * 20];
        _Float16*    prow = &Pl[q * PLD + part * 20];
        float m = -1e30f;
        float e[20];
        #pragma unroll
        for (int i = 0; i < 20; ++i) m = fmaxf(m, srow[i]);
        m = fmaxf(m, __shfl_xor(m, 1));
        m = fmaxf(m, __shfl_xor(m, 2));
        float ssum = 0.f;
        #pragma unroll
        for (int i = 0; i < 20; ++i) { e[i] = expf(srow[i] - m); ssum += e[i]; }
        ssum += __shfl_xor(ssum, 1);
        ssum += __shfl_xor(ssum, 2);
        const float inv = 1.f / ssum;
        #pragma unroll
        for (int i = 0; i < 20; ++i) prow[i] = (_Float16)(e[i] * inv);
        if (part == 3) {   // zero-pad c = 80..95 for the K=96 MFMA reduction
            #pragma unroll
            for (int i = 0; i < 16; ++i) Pl[q * PLD + 80 + i] = (_Float16)0.f;
        }
    }
    __syncthreads();

    // ---- Pass 2: PV via MFMA. out[q][d] = sum_c Pl[q][c] * K[c][d] ----
    // per 64-d chunk: stage Ks rows c=0..95 (clamped), then 2 waves x 4 d-tiles.
    const int dt_w = wv & 3;           // 0..3 (16-d tile within chunk)
    const int kr2b  = 64 + (t >> 3);   // rows 64..95 staged by t<256
    const int krow2b = (klo + kr2b) < (SEQ - 1) ? (klo + kr2b) : (SEQ - 1);
    const float* ksrc2b = keys + (size_t)krow2b * DIM + kc;

    for (int ch = 0; ch < 16; ++ch) {
        const int d0 = ch * 64;
        float4 kv0 = *(const float4*)(ksrc0 + d0);
        float4 kv1 = *(const float4*)(ksrc0 + d0 + 4);
        float4 kv2, kv3;
        if (t < 256) {
            kv2 = *(const float4*)(ksrc2b + d0);
            kv3 = *(const float4*)(ksrc2b + d0 + 4);
        }

        __syncthreads();   // previous chunk's fragment reads done

        half8 h0;
        h0[0] = (_Float16)kv0.x; h0[1] = (_Float16)kv0.y;
        h0[2] = (_Float16)kv0.z; h0[3] = (_Float16)kv0.w;
        h0[4] = (_Float16)kv1.x; h0[5] = (_Float16)kv1.y;
        h0[6] = (_Float16)kv1.z; h0[7] = (_Float16)kv1.w;
        *(half8*)&Ks[kr * KLD2 + kc] = h0;
        if (t < 256) {
            half8 h2;
            h2[0] = (_Float16)kv2.x; h2[1] = (_Float16)kv2.y;
            h2[2] = (_Float16)kv2.z; h2[3] = (_Float16)kv2.w;
            h2[4] = (_Float16)kv3.x; h2[5] = (_Float16)kv3.y;
            h2[6] = (_Float16)kv3.z; h2[7] = (_Float16)kv3.w;
            *(half8*)&Ks[kr2b * KLD2 + kc] = h2;
        }

        __syncthreads();

        f32x4 accO = {};
        #pragma unroll
        for (int s = 0; s < 3; ++s) {
            half8 af = *(const half8*)&Pl[(qt_w * 16 + l15) * PLD + s * 32 + quad * 8];
            half8 bf;
            #pragma unroll
            for (int j = 0; j < 8; ++j)
                bf[j] = Ks[(s * 32 + quad * 8 + j) * KLD2 + dt_w * 16 + l15];
            accO = __builtin_amdgcn_mfma_f32_16x16x32_f16(af, bf, accO, 0, 0, 0);
        }
        #pragma unroll
        for (int r = 0; r < 4; ++r)
            Out[((size_t)b * SEQ + q0 + qt_w * 16 + quad * 4 + r) * DIM + d0 + dt_w * 16 + l15] = accO[r];
    }
}

// ---------------------------------------------------------------------------
// Fallback GEMM (R3, known good): qt = Q @ W, fp32 in, fp32 out into d_out.
// ---------------------------------------------------------------------------
#define LDK 40
__global__ __launch_bounds__(256) void gemm_qw_f16(const float* __restrict__ Q,
                                                   const float* __restrict__ W,
                                                   float* __restrict__ QT) {
    __shared__ _Float16 Asl[128 * LDK];
    __shared__ _Float16 Bsl[128 * LDK];

    const int m0 = blockIdx.x * 128;
    const int n0 = blockIdx.y * 128;
    const int t  = threadIdx.x;
    const int lane = t & 63;
    const int wv   = t >> 6;
    const int wm   = (wv >> 1) * 64;
    const int wn   = (wv & 1) * 64;
    const int l15  = lane & 15;
    const int quad = lane >> 4;

    const int ar = t >> 1;
    const int ac = (t & 1) * 16;
    const float* Aptr = Q + (size_t)(m0 + ar) * DIM + ac;
    _Float16* AsW = &Asl[ar * LDK + ac];

    const int br = t >> 3;
    const int bc = t & 7;
    const float* Bptr = W + (size_t)br * DIM + n0 + bc;

    f32x4 acc[4][4] = {};

    for (int k0 = 0; k0 < DIM; k0 += 32) {
        float4 a0 = *(const float4*)(Aptr + k0);
        float4 a1 = *(const float4*)(Aptr + k0 + 4);
        float4 a2 = *(const float4*)(Aptr + k0 + 8);
        float4 a3 = *(const float4*)(Aptr + k0 + 12);
        float bv[16];
        #pragma unroll
        for (int j = 0; j < 16; ++j) bv[j] = Bptr[(size_t)k0 * DIM + 8 * j];

        __syncthreads();

        half8 h0, h1;
        h0[0] = (_Float16)a0.x; h0[1] = (_Float16)a0.y; h0[2] = (_Float16)a0.z; h0[3] = (_Float16)a0.w;
        h0[4] = (_Float16)a1.x; h0[5] = (_Float16)a1.y; h0[6] = (_Float16)a1.z; h0[7] = (_Float16)a1.w;
        h1[0] = (_Float16)a2.x; h1[1] = (_Float16)a2.y; h1[2] = (_Float16)a2.z; h1[3] = (_Float16)a2.w;
        h1[4] = (_Float16)a3.x; h1[5] = (_Float16)a3.y; h1[6] = (_Float16)a3.z; h1[7] = (_Float16)a3.w;
        *(half8*)(AsW)     = h0;
        *(half8*)(AsW + 8) = h1;

        #pragma unroll
        for (int j = 0; j < 16; ++j)
            Bsl[(bc + 8 * j) * LDK + br] = (_Float16)bv[j];

        __syncthreads();

        half8 af[4], bf[4];
        #pragma unroll
        for (int i = 0; i < 4; ++i)
            af[i] = *(const half8*)&Asl[(wm + i * 16 + l15) * LDK + quad * 8];
        #pragma unroll
        for (int j = 0; j < 4; ++j)
            bf[j] = *(const half8*)&Bsl[(wn + j * 16 + l15) * LDK + quad * 8];

        #pragma unroll
        for (int i = 0; i < 4; ++i)
            #pragma unroll
            for (int j = 0; j < 4; ++j)
                acc[i][j] = __builtin_amdgcn_mfma_f32_16x16x32_f16(af[i], bf[j], acc[i][j], 0, 0, 0);
    }

    #pragma unroll
    for (int i = 0; i < 4; ++i) {
        const int row0 = m0 + wm + i * 16 + quad * 4;
        #pragma unroll
        for (int r = 0; r < 4; ++r) {
            float* orow = QT + (size_t)(row0 + r) * DIM + n0 + wn + l15;
            #pragma unroll
            for (int j = 0; j < 4; ++j)
                orow[j * 16] = acc[i][j][r];
        }
    }
}

// ---------------------------------------------------------------------------
// Fallback attention (R4-verified): 16 q/block, LDS-staged, f32 QT in d_out.
// ---------------------------------------------------------------------------
#define TQ  16
#define KP  64
#define KLD 80
#define QLD 80
#define SLD 66

__global__ __launch_bounds__(256, 4) void attn_fb(const float* __restrict__ QT,
                                                  const float* __restrict__ Keys,
                                                  float* __restrict__ Out) {
    const int blk  = blockIdx.x;
    const int b    = blk & 7;
    const int tile = blk >> 3;
    const int q0   = tile * TQ;
    const int t    = threadIdx.x;
    const int lane = t & 63;
    const int wv   = t >> 6;
    const int l15  = lane & 15;
    const int quad = lane >> 4;

    const int klo = (q0 - WIN) > 0 ? (q0 - WIN) : 0;
    const int khi = (q0 + TQ - 1 + WIN) < (SEQ - 1) ? (q0 + TQ - 1 + WIN) : (SEQ - 1);
    const int nk  = khi - klo + 1;

    const float* qt   = QT + ((size_t)b * SEQ + q0) * DIM;
    const float* keys = Keys + (size_t)b * SEQ * DIM;

    __shared__ _Float16 Qc[TQ * QLD];
    __shared__ _Float16 Ks[KP * KLD];
    __shared__ float    Sl[TQ * SLD];
    __shared__ float    Wl[TQ * SLD];

    const int qr = t >> 4;
    const int qc = (t & 15) * 4;
    const int kr = t >> 2;
    const int kc = (t & 3) * 4;
    const int krow = (klo + kr) < (SEQ - 1) ? (klo + kr) : (SEQ - 1);

    const float* qsrc = qt + (size_t)qr * DIM + qc;
    const float* ksrc = keys + (size_t)krow * DIM + kc;

    f32x4 acc_s = {};

    for (int d0 = 0; d0 < DIM; d0 += 64) {
        const float4 qv = *(const float4*)(qsrc + d0);
        float4 kv0 = *(const float4*)(ksrc + d0);
        float4 kv1 = *(const float4*)(ksrc + d0 + 16);
        float4 kv2 = *(const float4*)(ksrc + d0 + 32);
        float4 kv3 = *(const float4*)(ksrc + d0 + 48);

        __syncthreads();

        half4v hq = {(_Float16)qv.x, (_Float16)qv.y, (_Float16)qv.z, (_Float16)qv.w};
        *(half4v*)&Qc[qr * QLD + qc] = hq;
        half4v h0 = {(_Float16)kv0.x, (_Float16)kv0.y, (_Float16)kv0.z, (_Float16)kv0.w};
        half4v h1 = {(_Float16)kv1.x, (_Float16)kv1.y, (_Float16)kv1.z, (_Float16)kv1.w};
        half4v h2 = {(_Float16)kv2.x, (_Float16)kv2.y, (_Float16)kv2.z, (_Float16)kv2.w};
        half4v h3 = {(_Float16)kv3.x, (_Float16)kv3.y, (_Float16)kv3.z, (_Float16)kv3.w};
        *(half4v*)&Ks[kr * KLD + kc]      = h0;
        *(half4v*)&Ks[kr * KLD + kc + 16] = h1;
        *(half4v*)&Ks[kr * KLD + kc + 32] = h2;
        *(half4v*)&Ks[kr * KLD + kc + 48] = h3;

        __syncthreads();

        #pragma unroll
        for (int s = 0; s < 2; ++s) {
            half8 af = *(const half8*)&Qc[l15 * QLD + s * 32 + quad * 8];
            half8 bf = *(const half8*)&Ks[(wv * 16 + l15) * KLD + s * 32 + quad * 8];
            acc_s = __builtin_amdgcn_mfma_f32_16x16x32_f16(af, bf, acc_s, 0, 0, 0);
        }
    }

    __syncthreads();
    #pragma unroll
    for (int r = 0; r < 4; ++r) {
        const int q = quad * 4 + r;
        const int c = wv * 16 + l15;
        const int d = (q0 + q) - (klo + c);
        const bool valid = (c < nk) && ((unsigned)(d + WIN) <= 2u * WIN);
        Sl[q * SLD + c] = valid ? acc_s[r] : -1e30f;
    }
    __syncthreads();

    if (t < 64) {
        const int q = t >> 2, part = t & 3;
        const float* srow = &Sl[q * SLD + part * 16];
        float*       wrow = &Wl[q * SLD + part * 16];
        float m = -1e30f;
        #pragma unroll
        for (int i = 0; i < 16; ++i) m = fmaxf(m, srow[i]);
        m = fmaxf(m, __shfl_xor(m, 1));
        m = fmaxf(m, __shfl_xor(m, 2));
        float ssum = 0.f;
        #pragma unroll
        for (int i = 0; i < 16; ++i) { float e = expf(srow[i] - m); wrow[i] = e; ssum += e; }
        ssum += __shfl_xor(ssum, 1);
        ssum += __shfl_xor(ssum, 2);
        const float inv = 1.f / ssum;
        #pragma unroll
        for (int i = 0; i < 16; ++i) wrow[i] *= inv;
    }
    __syncthreads();

    float accs[TQ][4] = {};
    for (int c = 0; c < nk; ++c) {
        const float* krow2 = keys + (size_t)(klo + c) * DIM;
        const float k0 = krow2[t], k1 = krow2[t + 256], k2 = krow2[t + 512], k3 = krow2[t + 768];
        #pragma unroll
        for (int q = 0; q < TQ; ++q) {
            const float w = Wl[q * SLD + c];
            accs[q][0] = fmaf(w, k0, accs[q][0]);
            accs[q][1] = fmaf(w, k1, accs[q][1]);
            accs[q][2] = fmaf(w, k2, accs[q][2]);
            accs[q][3] = fmaf(w, k3, accs[q][3]);
        }
    }
    #pragma unroll
    for (int q = 0; q < TQ; ++q) {
        float* orow = Out + ((size_t)b * SEQ + q0 + q) * DIM;
        orow[t]       = accs[q][0];
        orow[t + 256] = accs[q][1];
        orow[t + 512] = accs[q][2];
        orow[t + 768] = accs[q][3];
    }
}

extern "C" void kernel_launch(void* const* d_in, const int* in_sizes, int n_in,
                              void* d_out, int out_size, void* d_ws, size_t ws_size,
                              hipStream_t stream) {
    const float* queries = (const float*)d_in[0];
    const float* keys    = (const float*)d_in[1];
    const float* W       = (const float*)d_in[2];
    // d_in[3] (b_reduce): constant over k within a row -> cancels in softmax.
    float* out = (float*)d_out;

    const size_t qt16_bytes = (size_t)BATCH * SEQ * DIM * sizeof(_Float16);  // 33.5 MB
    const size_t w16_bytes  = (size_t)DIM * DIM * sizeof(_Float16);          //  2.0 MB

    if (ws_size >= qt16_bytes + w16_bytes) {
        // Fast path. Q16 lives in d_out (dead until attn overwrites it);
        // QT16 + W16T live in the workspace.
        _Float16* q16  = (_Float16*)d_out;
        _Float16* qt16 = (_Float16*)d_ws;
        _Float16* w16t = (_Float16*)((char*)d_ws + qt16_bytes);

        cvt_q_f16<<<2048, 256, 0, stream>>>(queries, q16);
        cvt_w_t<<<dim3(16, 16), 256, 0, stream>>>(W, w16t);
        gemm_f16t<<<dim3(8, 128), 256, 0, stream>>>(q16, w16t, qt16);
        const int nblk = (BATCH * SEQ) / TQV;   // 512
        attn_v5<<<nblk, 512, 0, stream>>>(qt16, keys, out);
    } else {
        // Fallback: R3-style path, fp32 QT through d_out, in-place attn.
        gemm_qw_f16<<<dim3(128, 8), 256, 0, stream>>>(queries, W, out);
        const int nblk = (BATCH * SEQ) / TQ;    // 1024
        attn_fb<<<nblk, 256, 0, stream>>>(out, keys, out);
    }
}

// Round 7
// 249.622 us; speedup vs baseline: 1.1970x; 1.0064x over previous
//
#include <hip/hip_runtime.h>

// B=8, S=2048, D=1024 banded attention, window +-20.
// out[b,q,:] = softmax_k( q^T W key_k , |q-k|<=20 ) @ keys
// b_reduce: per-q constant on every logit -> cancels in softmax -> unused.
//
// R10:
//  - gemm_f16t: XCD-grouped block swizzle (1D grid 1024). R9 counters showed
//    FETCH 132MB ~ 4x A: n-fastest grid put the 8 sharers of an A-panel on 8
//    DIFFERENT XCDs (xcd = bid%8 = n-tile). New map: xcd owns 16 contiguous
//    m-panels, n fastest inside -> A L2-shared, B (2MB) L2-resident per XCD.
//  - attn_v6: pass 2 drops K staging entirely. P is frozen in Pl; B-fragments
//    read straight from global keys (16 lanes x same row = 64B coalesced,
//    window L2-resident), cvt in-reg. Zero pass-2 barriers/LDS-staging.
// cvt_q_f16 / cvt_w_t / fallbacks unchanged.

#define BATCH 8
#define SEQ   2048
#define DIM   1024
#define WIN   20

typedef _Float16 half8  __attribute__((ext_vector_type(8)));
typedef _Float16 half4v __attribute__((ext_vector_type(4)));
typedef float    f32x4  __attribute__((ext_vector_type(4)));

#define GLOAD_LDS16(gsrc, ldst)                                                        \
    __builtin_amdgcn_global_load_lds(                                                  \
        (const __attribute__((address_space(1))) void*)(gsrc),                         \
        (__attribute__((address_space(3))) void*)(ldst), 16, 0, 0)

// ---------------------------------------------------------------------------
// Prep 1: Q fp32 -> f16, vectorized 8/thread, grid-stride.
// ---------------------------------------------------------------------------
__global__ __launch_bounds__(256) void cvt_q_f16(const float* __restrict__ in,
                                                 _Float16* __restrict__ out) {
    const int n8 = (BATCH * SEQ * DIM) / 8;
    for (int i = blockIdx.x * 256 + threadIdx.x; i < n8; i += gridDim.x * 256) {
        const float4 a = ((const float4*)in)[2 * i];
        const float4 b = ((const float4*)in)[2 * i + 1];
        half8 h;
        h[0] = (_Float16)a.x; h[1] = (_Float16)a.y; h[2] = (_Float16)a.z; h[3] = (_Float16)a.w;
        h[4] = (_Float16)b.x; h[5] = (_Float16)b.y; h[6] = (_Float16)b.z; h[7] = (_Float16)b.w;
        ((half8*)out)[i] = h;
    }
}

// ---------------------------------------------------------------------------
// Prep 2: W [k][n] fp32 -> WT [n][k] f16 (LDS tile transpose, 64x64 per block).
// ---------------------------------------------------------------------------
#define WTS 68
__global__ __launch_bounds__(256) void cvt_w_t(const float* __restrict__ W,
                                               _Float16* __restrict__ WT) {
    __shared__ _Float16 tile[64 * WTS];
    const int k0 = blockIdx.x * 64;
    const int n0 = blockIdx.y * 64;
    const int t  = threadIdx.x;
    const int r  = t >> 4;          // 0..15
    const int c4 = (t & 15) * 4;    // 0..60
    #pragma unroll
    for (int rr = 0; rr < 64; rr += 16) {
        float4 v = *(const float4*)&W[(size_t)(k0 + rr + r) * DIM + n0 + c4];
        _Float16* dst = &tile[(rr + r) * WTS + c4];
        dst[0] = (_Float16)v.x; dst[1] = (_Float16)v.y;
        dst[2] = (_Float16)v.z; dst[3] = (_Float16)v.w;
    }
    __syncthreads();
    #pragma unroll
    for (int rr = 0; rr < 64; rr += 16) {
        const int n = rr + r;
        half4v h = { tile[(c4 + 0) * WTS + n], tile[(c4 + 1) * WTS + n],
                     tile[(c4 + 2) * WTS + n], tile[(c4 + 3) * WTS + n] };
        *(half4v*)&WT[(size_t)(n0 + n) * DIM + k0 + c4] = h;
    }
}

// ---------------------------------------------------------------------------
// GEMM: C[m][n] = sum_k A[m][k] * B[n][k], all f16 (fp32 accum), C f16 out.
// 128x128 tile, BK=64, 4 waves, global_load_lds w=16, XOR-swizzled both sides.
// 1D grid 1024, XCD-grouped: bid = [m_hi4 | n3 | xcd3];
//   m_tile = xcd*16 + m_hi, n_tile = n3. Each XCD: contiguous 16-m slab,
//   n fastest -> A-panel L2-shared by its 8 sharers; B 2MB L2-resident.
// ---------------------------------------------------------------------------
#define GK 64
__global__ __launch_bounds__(256, 2) void gemm_f16t(const _Float16* __restrict__ A,
                                                    const _Float16* __restrict__ B,
                                                    _Float16* __restrict__ C) {
    __shared__ _Float16 As[128 * GK];   // 16 KB
    __shared__ _Float16 Bs[128 * GK];   // 16 KB

    const int bid  = blockIdx.x;
    const int m0   = (((bid & 7) << 4) | (bid >> 6)) * 128;
    const int n0   = ((bid >> 3) & 7) * 128;
    const int t    = threadIdx.x;
    const int lane = t & 63;
    const int wv   = t >> 6;
    const int wm   = (wv >> 1) * 64;
    const int wn   = (wv & 1) * 64;
    const int l15  = lane & 15;
    const int quad = lane >> 4;

    const int srow = lane >> 3;             // 0..7 : row within 8-row group
    const int sck  = (lane & 7) ^ srow;     // swizzled source 16B-chunk

    f32x4 acc[4][4] = {};

    for (int k0 = 0; k0 < DIM; k0 += GK) {
        __syncthreads();
        #pragma unroll
        for (int j = 0; j < 4; ++j) {
            const int rs = (j * 4 + wv) * 8;
            GLOAD_LDS16(A + (size_t)(m0 + rs + srow) * DIM + k0 + sck * 8, &As[rs * GK]);
            GLOAD_LDS16(B + (size_t)(n0 + rs + srow) * DIM + k0 + sck * 8, &Bs[rs * GK]);
        }
        __syncthreads();

        #pragma unroll
        for (int s = 0; s < 2; ++s) {
            half8 af[4], bf[4];
            #pragma unroll
            for (int i = 0; i < 4; ++i)
                af[i] = *(const half8*)&As[(wm + i * 16 + l15) * GK +
                                           (((s * 4 + quad) ^ (l15 & 7)) * 8)];
            #pragma unroll
            for (int j = 0; j < 4; ++j)
                bf[j] = *(const half8*)&Bs[(wn + j * 16 + l15) * GK +
                                           (((s * 4 + quad) ^ (l15 & 7)) * 8)];
            #pragma unroll
            for (int i = 0; i < 4; ++i)
                #pragma unroll
                for (int j = 0; j < 4; ++j)
                    acc[i][j] = __builtin_amdgcn_mfma_f32_16x16x32_f16(af[i], bf[j], acc[i][j], 0, 0, 0);
        }
    }

    #pragma unroll
    for (int i = 0; i < 4; ++i) {
        #pragma unroll
        for (int r = 0; r < 4; ++r) {
            _Float16* crow = C + (size_t)(m0 + wm + i * 16 + quad * 4 + r) * DIM + n0 + wn + l15;
            #pragma unroll
            for (int j = 0; j < 4; ++j)
                crow[j * 16] = (_Float16)acc[i][j][r];
        }
    }
}

// ---------------------------------------------------------------------------
// Banded attention v6: 32 queries/block, 512 threads (8 waves).
// Pass 1 (QK^T): LDS-staged as v4/v5. Softmax -> Pl f16 (zero-padded to 96).
// Pass 2 (PV): MFMA with A from Pl (LDS), B straight from global keys
// (cvt in-reg) -> no staging, no barriers.
// ---------------------------------------------------------------------------
#define TQV  32
#define KSR  80   // Ks rows (pass-1 staging only)
#define KLD2 80   // Ks stride (f16)
#define QLD2 80
#define SLD2 84   // Sl stride (f32)
#define PLD  104  // Pl stride (f16)

__global__ __launch_bounds__(512, 4) void attn_v6(const _Float16* __restrict__ QT,
                                                  const float* __restrict__ Keys,
                                                  float* __restrict__ Out) {
    const int blk  = blockIdx.x;
    const int b    = blk & 7;          // batch == XCD: keys L2-local
    const int tile = blk >> 3;         // 0..63
    const int q0   = tile * TQV;
    const int t    = threadIdx.x;
    const int lane = t & 63;
    const int wv   = t >> 6;           // 0..7
    const int l15  = lane & 15;
    const int quad = lane >> 4;

    const int klo = (q0 - WIN) > 0 ? (q0 - WIN) : 0;
    const int khi = (q0 + TQV - 1 + WIN) < (SEQ - 1) ? (q0 + TQV - 1 + WIN) : (SEQ - 1);
    const int nk  = khi - klo + 1;     // <= 72

    const float* keys = Keys + (size_t)b * SEQ * DIM;

    __shared__ _Float16 Qc[TQV * QLD2];   //  5.0 KB
    __shared__ _Float16 Ks[KSR * KLD2];   // 12.8 KB
    __shared__ float    Sl[TQV * SLD2];   // 10.8 KB
    __shared__ _Float16 Pl[TQV * PLD];    //  6.7 KB

    // ---- Pass 1: QK^T (LDS-staged, as v4/v5) ----
    const int qr = t >> 4;             // 0..31 (q row)
    const int qc = (t & 15) * 4;       // 0..60
    const int kr = t >> 3;             // 0..63 (key row, first batch)
    const int kc = (t & 7) * 8;        // 0,8,..,56
    const int krow0 = (klo + kr) < (SEQ - 1) ? (klo + kr) : (SEQ - 1);
    const int kr2   = 64 + (t >> 3);   // 64..79 (second batch, t<128)
    const int krow2 = (klo + kr2) < (SEQ - 1) ? (klo + kr2) : (SEQ - 1);

    const _Float16* qsrc  = QT + ((size_t)b * SEQ + q0 + qr) * DIM + qc;
    const float*    ksrc0 = keys + (size_t)krow0 * DIM + kc;
    const float*    ksrc2 = keys + (size_t)krow2 * DIM + kc;

    const int qt_w = wv >> 2;          // 0..1
    const int kt_a = wv & 3;           // 0..3
    const bool two = (kt_a == 0);      // this wave also does kt=4

    f32x4 acc0 = {}, acc1 = {};

    for (int d0 = 0; d0 < DIM; d0 += 64) {
        half4v hq = *(const half4v*)(qsrc + d0);
        float4 kv0 = *(const float4*)(ksrc0 + d0);
        float4 kv1 = *(const float4*)(ksrc0 + d0 + 4);
        float4 kv2, kv3;
        if (t < 128) {
            kv2 = *(const float4*)(ksrc2 + d0);
            kv3 = *(const float4*)(ksrc2 + d0 + 4);
        }

        __syncthreads();   // previous iteration's fragment reads done

        *(half4v*)&Qc[qr * QLD2 + qc] = hq;
        half8 h0;
        h0[0] = (_Float16)kv0.x; h0[1] = (_Float16)kv0.y;
        h0[2] = (_Float16)kv0.z; h0[3] = (_Float16)kv0.w;
        h0[4] = (_Float16)kv1.x; h0[5] = (_Float16)kv1.y;
        h0[6] = (_Float16)kv1.z; h0[7] = (_Float16)kv1.w;
        *(half8*)&Ks[kr * KLD2 + kc] = h0;
        if (t < 128) {
            half8 h2;
            h2[0] = (_Float16)kv2.x; h2[1] = (_Float16)kv2.y;
            h2[2] = (_Float16)kv2.z; h2[3] = (_Float16)kv2.w;
            h2[4] = (_Float16)kv3.x; h2[5] = (_Float16)kv3.y;
            h2[6] = (_Float16)kv3.z; h2[7] = (_Float16)kv3.w;
            *(half8*)&Ks[kr2 * KLD2 + kc] = h2;
        }

        __syncthreads();

        #pragma unroll
        for (int s = 0; s < 2; ++s) {
            half8 af = *(const half8*)&Qc[(qt_w * 16 + l15) * QLD2 + s * 32 + quad * 8];
            half8 bf0 = *(const half8*)&Ks[(kt_a * 16 + l15) * KLD2 + s * 32 + quad * 8];
            acc0 = __builtin_amdgcn_mfma_f32_16x16x32_f16(af, bf0, acc0, 0, 0, 0);
            if (two) {
                half8 bf1 = *(const half8*)&Ks[(4 * 16 + l15) * KLD2 + s * 32 + quad * 8];
                acc1 = __builtin_amdgcn_mfma_f32_16x16x32_f16(af, bf1, acc1, 0, 0, 0);
            }
        }
    }

    // logits -> Sl with band mask. C layout: col=l15 (key), row=quad*4+r (q).
    __syncthreads();
    #pragma unroll
    for (int r = 0; r < 4; ++r) {
        const int q = qt_w * 16 + quad * 4 + r;
        {
            const int c = kt_a * 16 + l15;
            const int d = (q0 + q) - (klo + c);
            const bool valid = (c < nk) && ((unsigned)(d + WIN) <= 2u * WIN);
            Sl[q * SLD2 + c] = valid ? acc0[r] : -1e30f;
        }
        if (two) {
            const int c = 64 + l15;
            const int d = (q0 + q) - (klo + c);
            const bool valid = (c < nk) && ((unsigned)(d + WIN) <= 2u * WIN);
            Sl[q * SLD2 + c] = valid ? acc1[r] : -1e30f;
        }
    }
    __syncthreads();

    // softmax: 128 threads, 4 lanes/q-row, 20 cols/lane; weights -> Pl f16.
    if (t < 128) {
        const int q = t >> 2, part = t & 3;
        const float* srow = &Sl[q * SLD2 + part * 20];
        _Float16*    prow = &Pl[q * PLD + part * 20];
        float m = -1e30f;
        float e[20];
        #pragma unroll
        for (int i = 0; i < 20; ++i) m = fmaxf(m, srow[i]);
        m = fmaxf(m, __shfl_xor(m, 1));
        m = fmaxf(m, __shfl_xor(m, 2));
        float ssum = 0.f;
        #pragma unroll
        for (int i = 0; i < 20; ++i) { e[i] = expf(srow[i] - m); ssum += e[i]; }
        ssum += __shfl_xor(ssum, 1);
        ssum += __shfl_xor(ssum, 2);
        const float inv = 1.f / ssum;
        #pragma unroll
        for (int i = 0; i < 20; ++i) prow[i] = (_Float16)(e[i] * inv);
        if (part == 3) {   // zero-pad c = 80..95 for the K=96 MFMA reduction
            #pragma unroll
            for (int i = 0; i < 16; ++i) Pl[q * PLD + 80 + i] = (_Float16)0.f;
        }
    }
    __syncthreads();   // Pl stable for the rest of the kernel

    // ---- Pass 2: PV via MFMA, B straight from global (no LDS, no barriers).
    // out[q][d] = sum_c Pl[q][c] * key[klo+c][d]; c padded to 96 (P=0 there).
    const int dt_w = wv & 3;           // 0..3 (16-d tile within 64-d chunk)
    // 24 clamped row offsets (elements), loop-invariant across chunks.
    for (int ch = 0; ch < 16; ++ch) {
        const int dcol = ch * 64 + dt_w * 16 + l15;
        const float* kcol = keys + dcol;
        f32x4 accO = {};
        #pragma unroll
        for (int s = 0; s < 3; ++s) {
            half8 af = *(const half8*)&Pl[(qt_w * 16 + l15) * PLD + s * 32 + quad * 8];
            half8 bf;
            #pragma unroll
            for (int j = 0; j < 8; ++j) {
                int c = s * 32 + quad * 8 + j;
                int kr3 = klo + c; if (kr3 > SEQ - 1) kr3 = SEQ - 1;
                bf[j] = (_Float16)kcol[(size_t)kr3 * DIM];
            }
            accO = __builtin_amdgcn_mfma_f32_16x16x32_f16(af, bf, accO, 0, 0, 0);
        }
        #pragma unroll
        for (int r = 0; r < 4; ++r)
            Out[((size_t)b * SEQ + q0 + qt_w * 16 + quad * 4 + r) * DIM + dcol] = accO[r];
    }
}

// ---------------------------------------------------------------------------
// Fallback GEMM (R3, known good): qt = Q @ W, fp32 in, fp32 out into d_out.
// ---------------------------------------------------------------------------
#define LDK 40
__global__ __launch_bounds__(256) void gemm_qw_f16(const float* __restrict__ Q,
                                                   const float* __restrict__ W,
                                                   float* __restrict__ QT) {
    __shared__ _Float16 Asl[128 * LDK];
    __shared__ _Float16 Bsl[128 * LDK];

    const int m0 = blockIdx.x * 128;
    const int n0 = blockIdx.y * 128;
    const int t  = threadIdx.x;
    const int lane = t & 63;
    const int wv   = t >> 6;
    const int wm   = (wv >> 1) * 64;
    const int wn   = (wv & 1) * 64;
    const int l15  = lane & 15;
    const int quad = lane >> 4;

    const int ar = t >> 1;
    const int ac = (t & 1) * 16;
    const float* Aptr = Q + (size_t)(m0 + ar) * DIM + ac;
    _Float16* AsW = &Asl[ar * LDK + ac];

    const int br = t >> 3;
    const int bc = t & 7;
    const float* Bptr = W + (size_t)br * DIM + n0 + bc;

    f32x4 acc[4][4] = {};

    for (int k0 = 0; k0 < DIM; k0 += 32) {
        float4 a0 = *(const float4*)(Aptr + k0);
        float4 a1 = *(const float4*)(Aptr + k0 + 4);
        float4 a2 = *(const float4*)(Aptr + k0 + 8);
        float4 a3 = *(const float4*)(Aptr + k0 + 12);
        float bv[16];
        #pragma unroll
        for (int j = 0; j < 16; ++j) bv[j] = Bptr[(size_t)k0 * DIM + 8 * j];

        __syncthreads();

        half8 h0, h1;
        h0[0] = (_Float16)a0.x; h0[1] = (_Float16)a0.y; h0[2] = (_Float16)a0.z; h0[3] = (_Float16)a0.w;
        h0[4] = (_Float16)a1.x; h0[5] = (_Float16)a1.y; h0[6] = (_Float16)a1.z; h0[7] = (_Float16)a1.w;
        h1[0] = (_Float16)a2.x; h1[1] = (_Float16)a2.y; h1[2] = (_Float16)a2.z; h1[3] = (_Float16)a2.w;
        h1[4] = (_Float16)a3.x; h1[5] = (_Float16)a3.y; h1[6] = (_Float16)a3.z; h1[7] = (_Float16)a3.w;
        *(half8*)(AsW)     = h0;
        *(half8*)(AsW + 8) = h1;

        #pragma unroll
        for (int j = 0; j < 16; ++j)
            Bsl[(bc + 8 * j) * LDK + br] = (_Float16)bv[j];

        __syncthreads();

        half8 af[4], bf[4];
        #pragma unroll
        for (int i = 0; i < 4; ++i)
            af[i] = *(const half8*)&Asl[(wm + i * 16 + l15) * LDK + quad * 8];
        #pragma unroll
        for (int j = 0; j < 4; ++j)
            bf[j] = *(const half8*)&Bsl[(wn + j * 16 + l15) * LDK + quad * 8];

        #pragma unroll
        for (int i = 0; i < 4; ++i)
            #pragma unroll
            for (int j = 0; j < 4; ++j)
                acc[i][j] = __builtin_amdgcn_mfma_f32_16x16x32_f16(af[i], bf[j], acc[i][j], 0, 0, 0);
    }

    #pragma unroll
    for (int i = 0; i < 4; ++i) {
        const int row0 = m0 + wm + i * 16 + quad * 4;
        #pragma unroll
        for (int r = 0; r < 4; ++r) {
            float* orow = QT + (size_t)(row0 + r) * DIM + n0 + wn + l15;
            #pragma unroll
            for (int j = 0; j < 4; ++j)
                orow[j * 16] = acc[i][j][r];
        }
    }
}

// ---------------------------------------------------------------------------
// Fallback attention (R4-verified): 16 q/block, LDS-staged, f32 QT in d_out.
// ---------------------------------------------------------------------------
#define TQ  16
#define KP  64
#define KLD 80
#define QLD 80
#define SLD 66

__global__ __launch_bounds__(256, 4) void attn_fb(const float* __restrict__ QT,
                                                  const float* __restrict__ Keys,
                                                  float* __restrict__ Out) {
    const int blk  = blockIdx.x;
    const int b    = blk & 7;
    const int tile = blk >> 3;
    const int q0   = tile * TQ;
    const int t    = threadIdx.x;
    const int lane = t & 63;
    const int wv   = t >> 6;
    const int l15  = lane & 15;
    const int quad = lane >> 4;

    const int klo = (q0 - WIN) > 0 ? (q0 - WIN) : 0;
    const int khi = (q0 + TQ - 1 + WIN) < (SEQ - 1) ? (q0 + TQ - 1 + WIN) : (SEQ - 1);
    const int nk  = khi - klo + 1;

    const float* qt   = QT + ((size_t)b * SEQ + q0) * DIM;
    const float* keys = Keys + (size_t)b * SEQ * DIM;

    __shared__ _Float16 Qc[TQ * QLD];
    __shared__ _Float16 Ks[KP * KLD];
    __shared__ float    Sl[TQ * SLD];
    __shared__ float    Wl[TQ * SLD];

    const int qr = t >> 4;
    const int qc = (t & 15) * 4;
    const int kr = t >> 2;
    const int kc = (t & 3) * 4;
    const int krow = (klo + kr) < (SEQ - 1) ? (klo + kr) : (SEQ - 1);

    const float* qsrc = qt + (size_t)qr * DIM + qc;
    const float* ksrc = keys + (size_t)krow * DIM + kc;

    f32x4 acc_s = {};

    for (int d0 = 0; d0 < DIM; d0 += 64) {
        const float4 qv = *(const float4*)(qsrc + d0);
        float4 kv0 = *(const float4*)(ksrc + d0);
        float4 kv1 = *(const float4*)(ksrc + d0 + 16);
        float4 kv2 = *(const float4*)(ksrc + d0 + 32);
        float4 kv3 = *(const float4*)(ksrc + d0 + 48);

        __syncthreads();

        half4v hq = {(_Float16)qv.x, (_Float16)qv.y, (_Float16)qv.z, (_Float16)qv.w};
        *(half4v*)&Qc[qr * QLD + qc] = hq;
        half4v h0 = {(_Float16)kv0.x, (_Float16)kv0.y, (_Float16)kv0.z, (_Float16)kv0.w};
        half4v h1 = {(_Float16)kv1.x, (_Float16)kv1.y, (_Float16)kv1.z, (_Float16)kv1.w};
        half4v h2 = {(_Float16)kv2.x, (_Float16)kv2.y, (_Float16)kv2.z, (_Float16)kv2.w};
        half4v h3 = {(_Float16)kv3.x, (_Float16)kv3.y, (_Float16)kv3.z, (_Float16)kv3.w};
        *(half4v*)&Ks[kr * KLD + kc]      = h0;
        *(half4v*)&Ks[kr * KLD + kc + 16] = h1;
        *(half4v*)&Ks[kr * KLD + kc + 32] = h2;
        *(half4v*)&Ks[kr * KLD + kc + 48] = h3;

        __syncthreads();

        #pragma unroll
        for (int s = 0; s < 2; ++s) {
            half8 af = *(const half8*)&Qc[l15 * QLD + s * 32 + quad * 8];
            half8 bf = *(const half8*)&Ks[(wv * 16 + l15) * KLD + s * 32 + quad * 8];
            acc_s = __builtin_amdgcn_mfma_f32_16x16x32_f16(af, bf, acc_s, 0, 0, 0);
        }
    }

    __syncthreads();
    #pragma unroll
    for (int r = 0; r < 4; ++r) {
        const int q = quad * 4 + r;
        const int c = wv * 16 + l15;
        const int d = (q0 + q) - (klo + c);
        const bool valid = (c < nk) && ((unsigned)(d + WIN) <= 2u * WIN);
        Sl[q * SLD + c] = valid ? acc_s[r] : -1e30f;
    }
    __syncthreads();

    if (t < 64) {
        const int q = t >> 2, part = t & 3;
        const float* srow = &Sl[q * SLD + part * 16];
        float*       wrow = &Wl[q * SLD + part * 16];
        float m = -1e30f;
        #pragma unroll
        for (int i = 0; i < 16; ++i) m = fmaxf(m, srow[i]);
        m = fmaxf(m, __shfl_xor(m, 1));
        m = fmaxf(m, __shfl_xor(m, 2));
        float ssum = 0.f;
        #pragma unroll
        for (int i = 0; i < 16; ++i) { float e = expf(srow[i] - m); wrow[i] = e; ssum += e; }
        ssum += __shfl_xor(ssum, 1);
        ssum += __shfl_xor(ssum, 2);
        const float inv = 1.f / ssum;
        #pragma unroll
        for (int i = 0; i < 16; ++i) wrow[i] *= inv;
    }
    __syncthreads();

    float accs[TQ][4] = {};
    for (int c = 0; c < nk; ++c) {
        const float* krow2 = keys + (size_t)(klo + c) * DIM;
        const float k0 = krow2[t], k1 = krow2[t + 256], k2 = krow2[t + 512], k3 = krow2[t + 768];
        #pragma unroll
        for (int q = 0; q < TQ; ++q) {
            const float w = Wl[q * SLD + c];
            accs[q][0] = fmaf(w, k0, accs[q][0]);
            accs[q][1] = fmaf(w, k1, accs[q][1]);
            accs[q][2] = fmaf(w, k2, accs[q][2]);
            accs[q][3] = fmaf(w, k3, accs[q][3]);
        }
    }
    #pragma unroll
    for (int q = 0; q < TQ; ++q) {
        float* orow = Out + ((size_t)b * SEQ + q0 + q) * DIM;
        orow[t]       = accs[q][0];
        orow[t + 256] = accs[q][1];
        orow[t + 512] = accs[q][2];
        orow[t + 768] = accs[q][3];
    }
}

extern "C" void kernel_launch(void* const* d_in, const int* in_sizes, int n_in,
                              void* d_out, int out_size, void* d_ws, size_t ws_size,
                              hipStream_t stream) {
    const float* queries = (const float*)d_in[0];
    const float* keys    = (const float*)d_in[1];
    const float* W       = (const float*)d_in[2];
    // d_in[3] (b_reduce): constant over k within a row -> cancels in softmax.
    float* out = (float*)d_out;

    const size_t qt16_bytes = (size_t)BATCH * SEQ * DIM * sizeof(_Float16);  // 33.5 MB
    const size_t w16_bytes  = (size_t)DIM * DIM * sizeof(_Float16);          //  2.0 MB

    if (ws_size >= qt16_bytes + w16_bytes) {
        // Fast path. Q16 lives in d_out (dead until attn overwrites it);
        // QT16 + W16T live in the workspace.
        _Float16* q16  = (_Float16*)d_out;
        _Float16* qt16 = (_Float16*)d_ws;
        _Float16* w16t = (_Float16*)((char*)d_ws + qt16_bytes);

        cvt_q_f16<<<2048, 256, 0, stream>>>(queries, q16);
        cvt_w_t<<<dim3(16, 16), 256, 0, stream>>>(W, w16t);
        gemm_f16t<<<1024, 256, 0, stream>>>(q16, w16t, qt16);
        const int nblk = (BATCH * SEQ) / TQV;   // 512
        attn_v6<<<nblk, 512, 0, stream>>>(qt16, keys, out);
    } else {
        // Fallback: R3-style path, fp32 QT through d_out, in-place attn.
        gemm_qw_f16<<<dim3(128, 8), 256, 0, stream>>>(queries, W, out);
        const int nblk = (BATCH * SEQ) / TQ;    // 1024
        attn_fb<<<nblk, 256, 0, stream>>>(out, keys, out);
    }
}